// Round 11
// baseline (262.869 us; speedup 1.0000x reference)
//
#include <hip/hip_runtime.h>
#include <hip/hip_bf16.h>
#include <math.h>

namespace {
constexpr int Bb = 2;
constexpr int Ll = 2048;
constexpr int Dd = 1024;
constexpr int Hh = 16;
constexpr int NT = Bb * Ll;   // 4096 tokens
constexpr int D3 = 3 * Dd;    // 3072
constexpr int PH = Dd / 2;    // 512 phases per token
}

typedef __attribute__((ext_vector_type(8))) short bf16x8;
typedef __attribute__((ext_vector_type(4))) float f32x4;

__device__ inline unsigned pack2bf(float a, float b) {
  __hip_bfloat162 t = __float22bfloat162_rn(float2{a, b});
  union { __hip_bfloat162 h; unsigned u; } cv; cv.h = t;
  return cv.u;
}

__device__ inline float bfhalf(unsigned u, int hi) {
  union { unsigned u; float f; } c;
  c.u = hi ? (u & 0xffff0000u) : (u << 16);
  return c.f;
}

__device__ inline unsigned merge2(unsigned u0, unsigned u1, float w0, float w1) {
  const float r0 = w0 * bfhalf(u0, 0) + w1 * bfhalf(u1, 0);
  const float r1 = w0 * bfhalf(u0, 1) + w1 * bfhalf(u1, 1);
  return pack2bf(r0, r1);
}

__device__ inline void async_cp16(const void* gsrc, void* ldst) {
  __builtin_amdgcn_global_load_lds(
      (const __attribute__((address_space(1))) unsigned int*)gsrc,
      (__attribute__((address_space(3))) unsigned int*)ldst, 16, 0, 0);
}

// ---------------- merged input prep: split_cast(p) + trans_split(proj) + cast3 ------
__global__ __launch_bounds__(256) void prep_kernel(
    const float4* __restrict__ p, uint2* __restrict__ p_hi4, uint2* __restrict__ p_lo4,
    const float* __restrict__ proj, short* __restrict__ th, short* __restrict__ tl,
    const float4* __restrict__ x, const float4* __restrict__ wq, const float4* __restrict__ wo,
    uint2* __restrict__ xd, uint2* __restrict__ wqd, uint2* __restrict__ wod)
{
  __shared__ float Ls[64][65];
  const int bid = blockIdx.x;
  const int tid = threadIdx.x;

  if (bid < 4096) {
    const int i = bid * 256 + tid;
    const float4 f = p[i];
    float hf[4], lf[4];
    const float ff[4] = {f.x, f.y, f.z, f.w};
#pragma unroll
    for (int j = 0; j < 4; ++j) {
      const __hip_bfloat16 h = __float2bfloat16(ff[j]);
      hf[j] = __bfloat162float(h);
      lf[j] = ff[j] - hf[j];
    }
    p_hi4[i] = make_uint2(pack2bf(hf[0], hf[1]), pack2bf(hf[2], hf[3]));
    p_lo4[i] = make_uint2(pack2bf(lf[0], lf[1]), pack2bf(lf[2], lf[3]));
  } else if (bid < 4224) {
    const int bx = bid - 4096;
    const int d0 = (bx & 15) * 64, m0 = (bx >> 4) * 64;
    const int r = tid >> 4, c4 = (tid & 15) * 4;
#pragma unroll
    for (int it = 0; it < 4; ++it) {
      const int row = it * 16 + r;
      const float4 v = *(const float4*)&proj[(size_t)(d0 + row) * PH + m0 + c4];
      Ls[row][c4] = v.x; Ls[row][c4+1] = v.y; Ls[row][c4+2] = v.z; Ls[row][c4+3] = v.w;
    }
    __syncthreads();
#pragma unroll
    for (int it = 0; it < 4; ++it) {
      const int row = it * 16 + r;
      float hf[4], lf[4];
#pragma unroll
      for (int j = 0; j < 4; ++j) {
        const float v = Ls[c4 + j][row];
        const __hip_bfloat16 h = __float2bfloat16(v);
        hf[j] = __bfloat162float(h);
        lf[j] = v - hf[j];
      }
      *(uint2*)&th[(size_t)(m0 + row) * Dd + d0 + c4] = make_uint2(pack2bf(hf[0], hf[1]), pack2bf(hf[2], hf[3]));
      *(uint2*)&tl[(size_t)(m0 + row) * Dd + d0 + c4] = make_uint2(pack2bf(lf[0], lf[1]), pack2bf(lf[2], lf[3]));
    }
  } else {
    int i = (bid - 4224) * 256 + tid;   // covers 2,097,152
    const float4* s; uint2* d;
    if (i < 1048576) { s = x; d = xd; }
    else if (i < 1048576 + 786432) { i -= 1048576; s = wq; d = wqd; }
    else { i -= 1048576 + 786432; s = wo; d = wod; }
    const float4 f = s[i];
    d[i] = make_uint2(pack2bf(f.x, f.y), pack2bf(f.z, f.w));
  }
}

// ---------------- split-bf16 MFMA GEMM for phases: 64n x 64m tile ------------------
// 3-buffer LDS pipeline, lookahead-2, counted vmcnt (4 loads/stage). The
// sched_barrier(0) after the barrier is REQUIRED: without it the compiler
// re-interleaves stage-issues/ds_reads around the hand-counted vmcnt (R7: -10us).
__global__ __launch_bounds__(256) void gemm_nn_split(
    const short* __restrict__ Ah_g, const short* __restrict__ Al_g,
    const short* __restrict__ Wh_g, const short* __restrict__ Wl_g,
    float* __restrict__ C)
{
  __shared__ __align__(16) short Ah[3][64 * 32], Al[3][64 * 32];
  __shared__ __align__(16) short Wh[3][64 * 32], Wl[3][64 * 32];
  const int tid = threadIdx.x;
  const int w = tid >> 6, lane = tid & 63;
  const int l15 = lane & 15, quad = lane >> 4;
  const int n0 = blockIdx.y * 64, m0 = blockIdx.x * 64;

  const int row = tid >> 2, cc = tid & 3;
  const int ksw = (cc ^ (row & 3)) * 8;
  const short* gAh = Ah_g + (size_t)(n0 + row) * Dd + ksw;
  const short* gAl = Al_g + (size_t)(n0 + row) * Dd + ksw;
  const short* gWh = Wh_g + (size_t)(m0 + row) * Dd + ksw;
  const short* gWl = Wl_g + (size_t)(m0 + row) * Dd + ksw;

  f32x4 acc[4];
#pragma unroll
  for (int j = 0; j < 4; ++j) acc[j] = f32x4{0.f, 0.f, 0.f, 0.f};

  const int swq = (quad ^ (l15 & 3)) * 8;

#define STAGE_NN(kv, bf) { \
  async_cp16(gAh + (kv), &Ah[bf][tid * 8]); \
  async_cp16(gAl + (kv), &Al[bf][tid * 8]); \
  async_cp16(gWh + (kv), &Wh[bf][tid * 8]); \
  async_cp16(gWl + (kv), &Wl[bf][tid * 8]); }

  STAGE_NN(0, 0);
  STAGE_NN(32, 1);
  int bi = 0;
  for (int k0 = 0; k0 < Dd; k0 += 32) {
    if (k0 + 32 < Dd) { asm volatile("s_waitcnt vmcnt(4)" ::: "memory"); }
    else              { asm volatile("s_waitcnt vmcnt(0)" ::: "memory"); }
    __builtin_amdgcn_s_barrier();
    __builtin_amdgcn_sched_barrier(0);
    if (k0 + 64 < Dd) { const int bn = (bi + 2 >= 3) ? bi - 1 : bi + 2; STAGE_NN(k0 + 64, bn); }

    bf16x8 ah, al, wh[4], wl[4];
    ah = *(const bf16x8*)&Ah[bi][(w * 16 + l15) * 32 + swq];
    al = *(const bf16x8*)&Al[bi][(w * 16 + l15) * 32 + swq];
#pragma unroll
    for (int j = 0; j < 4; ++j) {
      wh[j] = *(const bf16x8*)&Wh[bi][(j * 16 + l15) * 32 + swq];
      wl[j] = *(const bf16x8*)&Wl[bi][(j * 16 + l15) * 32 + swq];
    }
#pragma unroll
    for (int j = 0; j < 4; ++j) {
      acc[j] = __builtin_amdgcn_mfma_f32_16x16x32_bf16(ah, wh[j], acc[j], 0, 0, 0);
      acc[j] = __builtin_amdgcn_mfma_f32_16x16x32_bf16(ah, wl[j], acc[j], 0, 0, 0);
      acc[j] = __builtin_amdgcn_mfma_f32_16x16x32_bf16(al, wh[j], acc[j], 0, 0, 0);
    }
    bi = (bi == 2) ? 0 : bi + 1;
  }
#undef STAGE_NN

#pragma unroll
  for (int r = 0; r < 4; ++r) {
    float* crow = C + (size_t)(n0 + w * 16 + quad * 4 + r) * PH + m0 + l15;
#pragma unroll
    for (int j = 0; j < 4; ++j) crow[j * 16] = acc[j][r];
  }
}

// ---------------- qkv GEMM (3-buf counted-vmcnt pipeline) + fused rotary epilogue ---
// K and V are written in an XOR-swizzled tile layout so the attention kernel can
// stage them into LDS with linear global_load_lds AND read conflict-free:
//   K: element (token n, within-head d) stored at d ^ ((n&7)<<3)
//   V^T: element (d-row, token t) stored at t ^ ((d&7)<<3)
// sched_barrier(0) after the barrier is REQUIRED (see gemm_nn_split note).
__global__ __launch_bounds__(256) void gemm_qkv_fused(
    const __hip_bfloat16* __restrict__ A, const __hip_bfloat16* __restrict__ W,
    const float* __restrict__ bias, const float* __restrict__ phases,
    __hip_bfloat16* __restrict__ q_bf, __hip_bfloat16* __restrict__ k_bf,
    __hip_bfloat16* __restrict__ vt_g)
{
  __shared__ __align__(16) short As[3][128 * 32];
  __shared__ __align__(16) short Ws[3][128 * 32];
  const int tid = threadIdx.x;
  const int w = tid >> 6, lane = tid & 63;
  const int l15 = lane & 15, quad = lane >> 4;
  const int wn = w >> 1, wm = w & 1;
  const int n0 = blockIdx.y * 128, m0 = blockIdx.x * 128;

  const int row = tid >> 2, cc = tid & 3;
  const int ksw = (cc ^ (row & 3)) * 8;
  const short* gA  = (const short*)A + (size_t)(n0 + row) * Dd + ksw;
  const short* gW  = (const short*)W + (size_t)(m0 + row) * Dd + ksw;

  f32x4 acc[4][4];
#pragma unroll
  for (int i = 0; i < 4; ++i)
#pragma unroll
    for (int j = 0; j < 4; ++j) acc[i][j] = f32x4{0.f, 0.f, 0.f, 0.f};

  const int swq = (quad ^ (l15 & 3)) * 8;

#define STAGE_QKV(kv, bf) { \
  async_cp16(gA + (kv),            &As[bf][tid * 8]); \
  async_cp16(gA + 64 * Dd + (kv),  &As[bf][2048 + tid * 8]); \
  async_cp16(gW + (kv),            &Ws[bf][tid * 8]); \
  async_cp16(gW + 64 * Dd + (kv),  &Ws[bf][2048 + tid * 8]); }

  STAGE_QKV(0, 0);
  STAGE_QKV(32, 1);
  int bi = 0;
  for (int k0 = 0; k0 < Dd; k0 += 32) {
    if (k0 + 32 < Dd) { asm volatile("s_waitcnt vmcnt(4)" ::: "memory"); }
    else              { asm volatile("s_waitcnt vmcnt(0)" ::: "memory"); }
    __builtin_amdgcn_s_barrier();
    __builtin_amdgcn_sched_barrier(0);
    if (k0 + 64 < Dd) { const int bn = (bi + 2 >= 3) ? bi - 1 : bi + 2; STAGE_QKV(k0 + 64, bn); }

    bf16x8 af[4], bf[4];
#pragma unroll
    for (int i = 0; i < 4; ++i)
      af[i] = *(const bf16x8*)&As[bi][(wn * 64 + i * 16 + l15) * 32 + swq];
#pragma unroll
    for (int j = 0; j < 4; ++j)
      bf[j] = *(const bf16x8*)&Ws[bi][(wm * 64 + j * 16 + l15) * 32 + swq];
#pragma unroll
    for (int i = 0; i < 4; ++i)
#pragma unroll
      for (int j = 0; j < 4; ++j)
        acc[i][j] = __builtin_amdgcn_mfma_f32_16x16x32_bf16(af[i], bf[j], acc[i][j], 0, 0, 0);
    bi = (bi == 2) ? 0 : bi + 1;
  }
#undef STAGE_QKV

  float bv[4];
#pragma unroll
  for (int j = 0; j < 4; ++j) bv[j] = bias[m0 + wm * 64 + j * 16 + l15];

  const int region = m0 >> 10;                 // 0=q, 1=k, 2=v (block-uniform)
  const int mloc = (m0 & 1023) + wm * 64;
  const int h = mloc >> 6;

  if (region < 2) {
    __hip_bfloat16* dst = region == 0 ? q_bf : k_bf;
    const float SC = region == 0 ? 0.18033688011112042f : 1.0f;  // (1/8)*log2(e) on q
    const int dosw = (region == 1);
#pragma unroll
    for (int i = 0; i < 4; ++i)
#pragma unroll
      for (int r = 0; r < 4; ++r) {
        const int n = n0 + wn * 64 + i * 16 + quad * 4 + r;
        const int swz = dosw ? (((quad * 4 + r) & 7) << 3) : 0;   // == (n&7)<<3
        const float* phrow = phases + (size_t)n * PH + h * 32;
        __hip_bfloat16* drow = dst + (size_t)n * Dd + h * 64;
#pragma unroll
        for (int pz = 0; pz < 2; ++pz) {
          const float ph = phrow[pz * 16 + l15];
          float sn, cs;
          __sincosf(ph, &sn, &cs);
          const float a1 = acc[i][pz][r] + bv[pz];
          const float a2 = acc[i][pz + 2][r] + bv[pz + 2];
          drow[(pz * 16 + l15) ^ swz]      = __float2bfloat16((a1 * cs - a2 * sn) * SC);
          drow[(pz * 16 + 32 + l15) ^ swz] = __float2bfloat16((a1 * sn + a2 * cs) * SC);
        }
      }
  } else {
    const int bh = (n0 >> 11) * 16 + h;
    const int tokb = (n0 & 2047) + wn * 64;
    const int vsw = (l15 & 7) << 3;            // (d&7)<<3, d = j*16+l15
#pragma unroll
    for (int i = 0; i < 4; ++i)
#pragma unroll
      for (int j = 0; j < 4; ++j) {
        const uint2 o = make_uint2(
            pack2bf(acc[i][j][0] + bv[j], acc[i][j][1] + bv[j]),
            pack2bf(acc[i][j][2] + bv[j], acc[i][j][3] + bv[j]));
        const int d = j * 16 + l15;
        *(uint2*)&vt_g[(size_t)(bh * 64 + d) * Ll + tokb + ((i * 16 + quad * 4) ^ vsw)] = o;
      }
  }
}

// ---------------- out-proj GEMM with FUSED split-K combine (reg-dbuf A path) --------
// R8's stall: A-partial loads issued at iter tail had only ~400cy cover before the
// merge consumed them -> ~800cy exposed per iter (~11us). Fix: TWO register sets
// (E/O, compile-time named per rule #20) in an unroll-2 loop; each iteration loads
// the set for tile i+2 at the TOP (full-iteration cover) and merges the set loaded
// one full iteration earlier. The merge's compiler-inserted vmcnt wait retires
// W(i+1) (issued just before that A-set) -> Ws[i+1] provably complete before use.
__global__ __launch_bounds__(256) void gemm_bt_fused(
    const __hip_bfloat16* __restrict__ o_part,   // [2][NT][Dd] bf16 (normalized partials)
    const float* __restrict__ lden_g,            // [2][Bb][Hh][Ll] fp32
    const __hip_bfloat16* __restrict__ W,
    const float* __restrict__ bias, float* __restrict__ C)
{
  __shared__ __align__(16) short As[2][128 * 32];
  __shared__ __align__(16) short Ws[3][64 * 32];
  const int tid = threadIdx.x;
  const int w = tid >> 6, lane = tid & 63;
  const int l15 = lane & 15, quad = lane >> 4;
  const int n0 = blockIdx.y * 128, m0 = blockIdx.x * 64;

  const int row = tid >> 2, cc = tid & 3;
  const int ksw = (cc ^ (row & 3)) * 8;
  const short* gW = (const short*)W + (size_t)(m0 + row) * Dd + ksw;

  const int nA = n0 + row, nB = n0 + 64 + row;
  const __hip_bfloat16* gA = o_part + (size_t)nA * Dd + ksw;
  const __hip_bfloat16* gB = o_part + (size_t)nB * Dd + ksw;
  constexpr size_t ZOFF = (size_t)NT * Dd;     // z1 plane offset (elements)
  const int bA = nA >> 11, lAi = nA & 2047;
  const int bB = nB >> 11, lBi = nB & 2047;
  const float* ldA0 = lden_g + (size_t)bA * Hh * Ll + lAi;
  const float* ldA1 = lden_g + (size_t)(Bb + bA) * Hh * Ll + lAi;
  const float* ldB0 = lden_g + (size_t)bB * Hh * Ll + lBi;
  const float* ldB1 = lden_g + (size_t)(Bb + bB) * Hh * Ll + lBi;

  f32x4 acc[2][4];
#pragma unroll
  for (int i = 0; i < 2; ++i)
#pragma unroll
    for (int j = 0; j < 4; ++j) acc[i][j] = f32x4{0.f, 0.f, 0.f, 0.f};

  const int swq = (quad ^ (l15 & 3)) * 8;

  // two A register sets (even/odd tiles)
  uint4 paE0, paE1, pbE0, pbE1, paO0, paO1, pbO0, pbO1;
  float wE0, wE1, wE2, wE3, wO0, wO1, wO2, wO3;

#define ISSUE_W(kv, bf) async_cp16(gW + (kv), &Ws[bf][tid * 8]);
#define LD_SET(kv, P0, P1, P2, P3, L0, L1, L2, L3) { \
  const int h_ = ((kv) + ksw) >> 6; \
  L0 = ldA0[(size_t)h_ * Ll]; L1 = ldA1[(size_t)h_ * Ll]; \
  L2 = ldB0[(size_t)h_ * Ll]; L3 = ldB1[(size_t)h_ * Ll]; \
  P0 = *(const uint4*)(gA + (kv)); P1 = *(const uint4*)(gA + ZOFF + (kv)); \
  P2 = *(const uint4*)(gB + (kv)); P3 = *(const uint4*)(gB + ZOFF + (kv)); }
#define MERGE_FROM(P0, P1, P2, P3, L0, L1, L2, L3, buf) { \
  const float iA_ = 1.f / (L0 + L1); const float w0A_ = L0 * iA_, w1A_ = L1 * iA_; \
  const float iB_ = 1.f / (L2 + L3); const float w0B_ = L2 * iB_, w1B_ = L3 * iB_; \
  uint4 mA_, mB_; \
  mA_.x = merge2(P0.x, P1.x, w0A_, w1A_); mA_.y = merge2(P0.y, P1.y, w0A_, w1A_); \
  mA_.z = merge2(P0.z, P1.z, w0A_, w1A_); mA_.w = merge2(P0.w, P1.w, w0A_, w1A_); \
  mB_.x = merge2(P2.x, P3.x, w0B_, w1B_); mB_.y = merge2(P2.y, P3.y, w0B_, w1B_); \
  mB_.z = merge2(P2.z, P3.z, w0B_, w1B_); mB_.w = merge2(P2.w, P3.w, w0B_, w1B_); \
  *(uint4*)&As[buf][tid * 8] = mA_; *(uint4*)&As[buf][2048 + tid * 8] = mB_; }

#define MFMA_TILE(abuf, wslot) { \
  bf16x8 af[2], bf[4]; \
  _Pragma("unroll") \
  for (int ii = 0; ii < 2; ++ii) \
    af[ii] = *(const bf16x8*)&As[abuf][(w * 32 + ii * 16 + l15) * 32 + swq]; \
  _Pragma("unroll") \
  for (int j = 0; j < 4; ++j) \
    bf[j] = *(const bf16x8*)&Ws[wslot][(j * 16 + l15) * 32 + swq]; \
  _Pragma("unroll") \
  for (int ii = 0; ii < 2; ++ii) \
    _Pragma("unroll") \
    for (int j = 0; j < 4; ++j) \
      acc[ii][j] = __builtin_amdgcn_mfma_f32_16x16x32_bf16(af[ii], bf[j], acc[ii][j], 0, 0, 0); }

  // prologue: tile0 -> E -> As[0]; tile1 -> O (merged at iter 0)
  ISSUE_W(0, 0);
  LD_SET(0, paE0, paE1, pbE0, pbE1, wE0, wE1, wE2, wE3);
  MERGE_FROM(paE0, paE1, pbE0, pbE1, wE0, wE1, wE2, wE3, 0);   // implicit wait drains W(0)+A(0)
  ISSUE_W(32, 1);
  LD_SET(32, paO0, paO1, pbO0, pbO1, wO0, wO1, wO2, wO3);
  asm volatile("s_waitcnt lgkmcnt(0)" ::: "memory");
  __builtin_amdgcn_s_barrier();
  __builtin_amdgcn_sched_barrier(0);

  for (int ip = 0; ip < 16; ++ip) {
    const int i0 = 2 * ip;        // even iter: compute tile i0 from As[0]
    {
      const int k0 = i0 * 32;
      if (i0 + 2 < 32) {
        ISSUE_W(k0 + 64, (i0 + 2) % 3);
        LD_SET(k0 + 64, paE0, paE1, pbE0, pbE1, wE0, wE1, wE2, wE3);   // tile i0+2 -> E
      }
      MFMA_TILE(0, i0 % 3);
      // merge tile i0+1 (O set, loaded a full iteration ago); its vmcnt wait also
      // retires W(i0+1) which was issued just before that O load.
      MERGE_FROM(paO0, paO1, pbO0, pbO1, wO0, wO1, wO2, wO3, 1);
      asm volatile("s_waitcnt lgkmcnt(0)" ::: "memory");
      __builtin_amdgcn_s_barrier();
      __builtin_amdgcn_sched_barrier(0);
    }
    const int i1 = i0 + 1;        // odd iter: compute tile i1 from As[1]
    {
      const int k1 = i1 * 32;
      if (i1 + 2 < 32) {
        ISSUE_W(k1 + 64, (i1 + 2) % 3);
        LD_SET(k1 + 64, paO0, paO1, pbO0, pbO1, wO0, wO1, wO2, wO3);   // tile i1+2 -> O
      }
      MFMA_TILE(1, i1 % 3);
      if (i1 + 1 < 32) {
        MERGE_FROM(paE0, paE1, pbE0, pbE1, wE0, wE1, wE2, wE3, 0);     // tile i1+1 -> As[0]
        asm volatile("s_waitcnt lgkmcnt(0)" ::: "memory");
        __builtin_amdgcn_s_barrier();
        __builtin_amdgcn_sched_barrier(0);
      }
    }
  }
#undef ISSUE_W
#undef LD_SET
#undef MERGE_FROM
#undef MFMA_TILE

  float bv[4];
#pragma unroll
  for (int j = 0; j < 4; ++j) bv[j] = bias[m0 + j * 16 + l15];
#pragma unroll
  for (int i = 0; i < 2; ++i)
#pragma unroll
    for (int r = 0; r < 4; ++r) {
      float* crow = C + (size_t)(n0 + w * 32 + i * 16 + quad * 4 + r) * Dd + m0 + l15;
#pragma unroll
      for (int j = 0; j < 4; ++j) crow[j * 16] = acc[i][j][r] + bv[j];
    }
}

// ---------------- bf16 MFMA flash attention (split-K, pipelined QK(kt+1) ∥ exp(kt)) -
// Q-tile 128, K-tile 64, blockIdx.z selects kt half [z*16, z*16+16). Grid 1024.
// Software pipeline (T15-style): QK^T of tile kt+1 (MFMA pipe) is issued alongside
// exp2/pack of tile kt (VALU/trans pipe); PV(kt) closes each phase. K is staged
// with lookahead 2 into Kb[2], V with lookahead 1 into Vb[2]; one barrier per kt.
__global__ __launch_bounds__(256) void attn_mfma(
    const __hip_bfloat16* __restrict__ q_bf,
    const __hip_bfloat16* __restrict__ k_bf,
    const __hip_bfloat16* __restrict__ vt_g,
    __hip_bfloat16* __restrict__ o_part,   // [2][NT][Dd] bf16
    float* __restrict__ lden_g)            // [2][Bb][Hh][Ll] fp32
{
  __shared__ __align__(16) short Kb[2][4096];
  __shared__ __align__(16) short Vb[2][4096];

  const int tid = threadIdx.x;
  const int w = tid >> 6;
  const int lane = tid & 63;
  const int l15 = lane & 15;
  const int quad = lane >> 4;

  const int q0 = blockIdx.x * 128;
  const int bh = blockIdx.y;
  const int kz = blockIdx.z;
  const int b = bh >> 4, h = bh & 15;
  const int kt0 = kz * 16;

  bf16x8 qfrag[2][2];
#pragma unroll
  for (int qg = 0; qg < 2; ++qg)
#pragma unroll
    for (int kh = 0; kh < 2; ++kh) {
      const size_t qrow = (size_t)(b * Ll + q0 + w * 32 + qg * 16 + l15);
      qfrag[qg][kh] = *(const bf16x8*)(q_bf + qrow * Dd + h * 64 + kh * 32 + quad * 8);
    }

  f32x4 acc[4][2];
#pragma unroll
  for (int dt = 0; dt < 4; ++dt)
#pragma unroll
    for (int qg = 0; qg < 2; ++qg) acc[dt][qg] = f32x4{0.f, 0.f, 0.f, 0.f};
  f32x4 lden[2] = {f32x4{0.f,0.f,0.f,0.f}, f32x4{0.f,0.f,0.f,0.f}};
  const f32x4 zro = {0.f, 0.f, 0.f, 0.f};
  const short one_bf = (short)0x3F80;           // bf16 1.0
  const bf16x8 ones8 = {one_bf, one_bf, one_bf, one_bf, one_bf, one_bf, one_bf, one_bf};

  // staging: thread tid copies 16B of row (tid>>3) (+32 rows) at byte col (tid&7)*16
  const __hip_bfloat16* ksrc = k_bf + ((size_t)(b * Ll) + (tid >> 3)) * Dd + h * 64 + (tid & 7) * 8;
  const __hip_bfloat16* vsrc = vt_g + ((size_t)(bh * 64) + (tid >> 3)) * Ll + (tid & 7) * 8;
  const int ldst = tid * 8;   // shorts offset within a 4096-short plane

  // swizzled column offsets (shorts): logical col ^ ((row&7)<<3)
  const int sw = (l15 & 7) << 3;
  const int co0 = (quad * 8) ^ sw;
  const int co1 = (32 + quad * 8) ^ sw;

#define STAGE_K(t, bf) { const __hip_bfloat16* kp_ = ksrc + (size_t)(t) * 64 * Dd; \
  async_cp16(kp_, &Kb[bf][ldst]); async_cp16(kp_ + (size_t)32 * Dd, &Kb[bf][2048 + ldst]); }
#define STAGE_V(t, bf) { const __hip_bfloat16* vp_ = vsrc + (size_t)(t) * 64; \
  async_cp16(vp_, &Vb[bf][ldst]); async_cp16(vp_ + (size_t)32 * Ll, &Vb[bf][2048 + ldst]); }

  f32x4 s[4][2];

#define QK_N(Ks, n) { \
  const bf16x8 af0_ = *(const bf16x8*)&(Ks)[((n) * 16 + l15) * 64 + co0]; \
  const bf16x8 af1_ = *(const bf16x8*)&(Ks)[((n) * 16 + l15) * 64 + co1]; \
  s[n][0] = __builtin_amdgcn_mfma_f32_16x16x32_bf16(af0_, qfrag[0][0], zro, 0, 0, 0); \
  s[n][1] = __builtin_amdgcn_mfma_f32_16x16x32_bf16(af0_, qfrag[1][0], zro, 0, 0, 0); \
  s[n][0] = __builtin_amdgcn_mfma_f32_16x16x32_bf16(af1_, qfrag[0][1], s[n][0], 0, 0, 0); \
  s[n][1] = __builtin_amdgcn_mfma_f32_16x16x32_bf16(af1_, qfrag[1][1], s[n][1], 0, 0, 0); }

#define EXPPACK(v, dst) { union { float f; unsigned u; } p0_, p1_, p2_, p3_; \
  p0_.f = __builtin_amdgcn_exp2f((v)[0]); p1_.f = __builtin_amdgcn_exp2f((v)[1]); \
  p2_.f = __builtin_amdgcn_exp2f((v)[2]); p3_.f = __builtin_amdgcn_exp2f((v)[3]); \
  dst = make_uint2(__builtin_amdgcn_perm(p1_.u, p0_.u, 0x07060302u), \
                   __builtin_amdgcn_perm(p3_.u, p2_.u, 0x07060302u)); }

#define PV_QG(va, aU, cU, qg) { \
  auto rx32_ = __builtin_amdgcn_permlane32_swap((aU).x, (cU).x, false, false); \
  auto rx16_ = __builtin_amdgcn_permlane16_swap(rx32_[0], rx32_[1], false, false); \
  auto ry32_ = __builtin_amdgcn_permlane32_swap((aU).y, (cU).y, false, false); \
  auto ry16_ = __builtin_amdgcn_permlane16_swap(ry32_[0], ry32_[1], false, false); \
  union { unsigned u[4]; bf16x8 v; } pb_; \
  pb_.u[0] = rx16_[0]; pb_.u[1] = ry16_[0]; pb_.u[2] = rx16_[1]; pb_.u[3] = ry16_[1]; \
  lden[qg] = __builtin_amdgcn_mfma_f32_16x16x32_bf16(ones8, pb_.v, lden[qg], 0, 0, 0); \
  acc[0][qg] = __builtin_amdgcn_mfma_f32_16x16x32_bf16(va[0], pb_.v, acc[0][qg], 0, 0, 0); \
  acc[1][qg] = __builtin_amdgcn_mfma_f32_16x16x32_bf16(va[1], pb_.v, acc[1][qg], 0, 0, 0); \
  acc[2][qg] = __builtin_amdgcn_mfma_f32_16x16x32_bf16(va[2], pb_.v, acc[2][qg], 0, 0, 0); \
  acc[3][qg] = __builtin_amdgcn_mfma_f32_16x16x32_bf16(va[3], pb_.v, acc[3][qg], 0, 0, 0); }

  // prologue: K(0) -> Kb[0]; after barrier, start K(1),V(0) and compute QK(0)
  STAGE_K(kt0, 0);
  __syncthreads();
  STAGE_K(kt0 + 1, 1);
  STAGE_V(kt0, 0);
  __builtin_amdgcn_s_setprio(1);
  QK_N(Kb[0], 0); QK_N(Kb[0], 1); QK_N(Kb[0], 2); QK_N(Kb[0], 3);
  __builtin_amdgcn_s_setprio(0);

  for (int i = 0; i < 16; ++i) {
    __syncthreads();   // implicit vmcnt(0): K(i+1),V(i) staged; all prev reads done
    if (i + 2 < 16) STAGE_K(kt0 + i + 2, i & 1);
    if (i + 1 < 16) STAGE_V(kt0 + i + 1, (i + 1) & 1);
    const short* Kn = &Kb[(i + 1) & 1][0];
    const short* Vc = &Vb[i & 1][0];
    const bool doqk = (i + 1 < 16);

    // ---- phase 0: exp/pack P rows 0..31 ∥ QK(i+1) rows 0..31, then PV pr=0 ----
    uint2 a0, a1, c0, c1;
    EXPPACK(s[0][0], a0); EXPPACK(s[0][1], a1);
    EXPPACK(s[1][0], c0); EXPPACK(s[1][1], c1);
    if (doqk) {
      __builtin_amdgcn_s_setprio(1);
      QK_N(Kn, 0); QK_N(Kn, 1);
      __builtin_amdgcn_s_setprio(0);
    }
    {
      bf16x8 va[4];
#pragma unroll
      for (int dt = 0; dt < 4; ++dt)
        va[dt] = *(const bf16x8*)&Vc[(dt * 16 + l15) * 64 + co0];
      __builtin_amdgcn_s_setprio(1);
      PV_QG(va, a0, c0, 0);
      PV_QG(va, a1, c1, 1);
      __builtin_amdgcn_s_setprio(0);
    }

    // ---- phase 1: exp/pack P rows 32..63 ∥ QK(i+1) rows 32..63, then PV pr=1 ----
    uint2 a2, a3, c2, c3;
    EXPPACK(s[2][0], a2); EXPPACK(s[2][1], a3);
    EXPPACK(s[3][0], c2); EXPPACK(s[3][1], c3);
    if (doqk) {
      __builtin_amdgcn_s_setprio(1);
      QK_N(Kn, 2); QK_N(Kn, 3);
      __builtin_amdgcn_s_setprio(0);
    }
    {
      bf16x8 va[4];
#pragma unroll
      for (int dt = 0; dt < 4; ++dt)
        va[dt] = *(const bf16x8*)&Vc[(dt * 16 + l15) * 64 + co1];
      __builtin_amdgcn_s_setprio(1);
      PV_QG(va, a2, c2, 0);
      PV_QG(va, a3, c3, 1);
      __builtin_amdgcn_s_setprio(0);
    }
  }

#undef STAGE_K
#undef STAGE_V
#undef QK_N
#undef EXPPACK
#undef PV_QG

#pragma unroll
  for (int qg = 0; qg < 2; ++qg) {
    const float lv = lden[qg][0];           // all rows identical; col l15 = this q
    const float linv = 1.f / lv;
    const int ql = q0 + w * 32 + qg * 16 + l15;
    if (quad == 0)
      lden_g[((size_t)(kz * Bb + b) * Hh + h) * Ll + ql] = lv;
    __hip_bfloat16* dst = o_part + ((size_t)kz * NT + b * Ll + ql) * Dd + h * 64;
#pragma unroll
    for (int dt = 0; dt < 4; ++dt) {
      const uint2 o = make_uint2(
          pack2bf(acc[dt][qg][0] * linv, acc[dt][qg][1] * linv),
          pack2bf(acc[dt][qg][2] * linv, acc[dt][qg][3] * linv));
      *(uint2*)&dst[dt * 16 + quad * 4] = o;
    }
  }
}

extern "C" void kernel_launch(void* const* d_in, const int* in_sizes, int n_in,
                              void* d_out, int out_size, void* d_ws, size_t ws_size,
                              hipStream_t stream) {
  const float* x     = (const float*)d_in[0];
  const float* p     = (const float*)d_in[1];
  const float* W_qkv = (const float*)d_in[2];
  const float* b_qkv = (const float*)d_in[3];
  const float* W_out = (const float*)d_in[4];
  const float* b_out = (const float*)d_in[5];
  const float* proj  = (const float*)d_in[6];
  float* out = (float*)d_out;

  // workspace overlay (~61 MiB):
  //  [0,8Mi):   phases fp32
  //  [8,16Mi):  p_hi
  //  [16,24Mi): p_lo  -> (dead after phases gemm) vt_g
  //  [24,25Mi): projt_hi   [25,26Mi): projt_lo
  //  [26,34Mi): q_bf   [34,42Mi): k_bf
  //  [42,50Mi): x_bf     -> (dead after qkv gemm) o_part z0
  //  [50,56Mi): wqkv_bf  -> (dead after qkv gemm) o_part z1 [50,58Mi)
  //  [58,60Mi): wout_bf
  //  [60,60.5Mi): lden_g
  char* wsb = (char*)d_ws;
  float*          phases   = (float*)(wsb);
  short*          p_hi     = (short*)(wsb + (8u << 20));
  short*          p_lo     = (short*)(wsb + (16u << 20));
  __hip_bfloat16* vt_g     = (__hip_bfloat16*)(wsb + (16u << 20));
  short*          projt_hi = (short*)(wsb + (24u << 20));
  short*          projt_lo = (short*)(wsb + (25u << 20));
  __hip_bfloat16* q_bf     = (__hip_bfloat16*)(wsb + (26u << 20));
  __hip_bfloat16* k_bf     = (__hip_bfloat16*)(wsb + (34u << 20));
  __hip_bfloat16* x_bf     = (__hip_bfloat16*)(wsb + (42u << 20));
  __hip_bfloat16* o_part   = (__hip_bfloat16*)(wsb + (42u << 20));
  __hip_bfloat16* wqkv_bf  = (__hip_bfloat16*)(wsb + (50u << 20));
  __hip_bfloat16* wout_bf  = (__hip_bfloat16*)(wsb + (58u << 20));
  float*          lden_g   = (float*)(wsb + (60u << 20));

  // merged input prep
  prep_kernel<<<12416, 256, 0, stream>>>(
      (const float4*)p, (uint2*)p_hi, (uint2*)p_lo,
      proj, projt_hi, projt_lo,
      (const float4*)x, (const float4*)W_qkv, (const float4*)W_out,
      (uint2*)x_bf, (uint2*)wqkv_bf, (uint2*)wout_bf);
  // phases = p @ proj (split-bf16), 64x64 tiles -> 512 blocks (2/CU)
  gemm_nn_split<<<dim3(PH / 64, NT / 64), 256, 0, stream>>>(p_hi, p_lo, projt_hi, projt_lo, phases);
  // qkv GEMM + fused rotary/cast/swizzled V/K epilogue
  gemm_qkv_fused<<<dim3(D3 / 128, NT / 128), 256, 0, stream>>>(x_bf, wqkv_bf, b_qkv, phases,
                                                               q_bf, k_bf, vt_g);
  // flash attention (split-K halves, pipelined) -> partials
  attn_mfma<<<dim3(Ll / 128, Bb * Hh, 2), 256, 0, stream>>>(q_bf, k_bf, vt_g, o_part, lden_g);
  // out = combine(o_part) @ W_out^T + b_out, combine fused into A-staging (reg-dbuf)
  gemm_bt_fused<<<dim3(Dd / 64, NT / 128), 256, 0, stream>>>(o_part, lden_g, wout_bf, b_out, out);
}

// Round 12
// 254.528 us; speedup vs baseline: 1.0328x; 1.0328x over previous
//
#include <hip/hip_runtime.h>
#include <hip/hip_bf16.h>
#include <math.h>

namespace {
constexpr int Bb = 2;
constexpr int Ll = 2048;
constexpr int Dd = 1024;
constexpr int Hh = 16;
constexpr int NT = Bb * Ll;   // 4096 tokens
constexpr int D3 = 3 * Dd;    // 3072
constexpr int PH = Dd / 2;    // 512 phases per token
}

typedef __attribute__((ext_vector_type(8))) short bf16x8;
typedef __attribute__((ext_vector_type(4))) float f32x4;

__device__ inline unsigned pack2bf(float a, float b) {
  __hip_bfloat162 t = __float22bfloat162_rn(float2{a, b});
  union { __hip_bfloat162 h; unsigned u; } cv; cv.h = t;
  return cv.u;
}

__device__ inline float bfhalf(unsigned u, int hi) {
  union { unsigned u; float f; } c;
  c.u = hi ? (u & 0xffff0000u) : (u << 16);
  return c.f;
}

__device__ inline void async_cp16(const void* gsrc, void* ldst) {
  __builtin_amdgcn_global_load_lds(
      (const __attribute__((address_space(1))) unsigned int*)gsrc,
      (__attribute__((address_space(3))) unsigned int*)ldst, 16, 0, 0);
}

// ---------------- merged input prep: split_cast(p) + trans_split(proj) + cast3 ------
__global__ __launch_bounds__(256) void prep_kernel(
    const float4* __restrict__ p, uint2* __restrict__ p_hi4, uint2* __restrict__ p_lo4,
    const float* __restrict__ proj, short* __restrict__ th, short* __restrict__ tl,
    const float4* __restrict__ x, const float4* __restrict__ wq, const float4* __restrict__ wo,
    uint2* __restrict__ xd, uint2* __restrict__ wqd, uint2* __restrict__ wod)
{
  __shared__ float Ls[64][65];
  const int bid = blockIdx.x;
  const int tid = threadIdx.x;

  if (bid < 4096) {
    const int i = bid * 256 + tid;
    const float4 f = p[i];
    float hf[4], lf[4];
    const float ff[4] = {f.x, f.y, f.z, f.w};
#pragma unroll
    for (int j = 0; j < 4; ++j) {
      const __hip_bfloat16 h = __float2bfloat16(ff[j]);
      hf[j] = __bfloat162float(h);
      lf[j] = ff[j] - hf[j];
    }
    p_hi4[i] = make_uint2(pack2bf(hf[0], hf[1]), pack2bf(hf[2], hf[3]));
    p_lo4[i] = make_uint2(pack2bf(lf[0], lf[1]), pack2bf(lf[2], lf[3]));
  } else if (bid < 4224) {
    const int bx = bid - 4096;
    const int d0 = (bx & 15) * 64, m0 = (bx >> 4) * 64;
    const int r = tid >> 4, c4 = (tid & 15) * 4;
#pragma unroll
    for (int it = 0; it < 4; ++it) {
      const int row = it * 16 + r;
      const float4 v = *(const float4*)&proj[(size_t)(d0 + row) * PH + m0 + c4];
      Ls[row][c4] = v.x; Ls[row][c4+1] = v.y; Ls[row][c4+2] = v.z; Ls[row][c4+3] = v.w;
    }
    __syncthreads();
#pragma unroll
    for (int it = 0; it < 4; ++it) {
      const int row = it * 16 + r;
      float hf[4], lf[4];
#pragma unroll
      for (int j = 0; j < 4; ++j) {
        const float v = Ls[c4 + j][row];
        const __hip_bfloat16 h = __float2bfloat16(v);
        hf[j] = __bfloat162float(h);
        lf[j] = v - hf[j];
      }
      *(uint2*)&th[(size_t)(m0 + row) * Dd + d0 + c4] = make_uint2(pack2bf(hf[0], hf[1]), pack2bf(hf[2], hf[3]));
      *(uint2*)&tl[(size_t)(m0 + row) * Dd + d0 + c4] = make_uint2(pack2bf(lf[0], lf[1]), pack2bf(lf[2], lf[3]));
    }
  } else {
    int i = (bid - 4224) * 256 + tid;   // covers 2,097,152
    const float4* s; uint2* d;
    if (i < 1048576) { s = x; d = xd; }
    else if (i < 1048576 + 786432) { i -= 1048576; s = wq; d = wqd; }
    else { i -= 1048576 + 786432; s = wo; d = wod; }
    const float4 f = s[i];
    d[i] = make_uint2(pack2bf(f.x, f.y), pack2bf(f.z, f.w));
  }
}

// ---------------- split-bf16 MFMA GEMM for phases: 64n x 64m tile ------------------
// 3-buffer LDS pipeline, lookahead-2, counted vmcnt (4 loads/stage). The
// sched_barrier(0) after the barrier is REQUIRED: without it the compiler
// re-interleaves stage-issues/ds_reads around the hand-counted vmcnt (R7: -10us).
__global__ __launch_bounds__(256) void gemm_nn_split(
    const short* __restrict__ Ah_g, const short* __restrict__ Al_g,
    const short* __restrict__ Wh_g, const short* __restrict__ Wl_g,
    float* __restrict__ C)
{
  __shared__ __align__(16) short Ah[3][64 * 32], Al[3][64 * 32];
  __shared__ __align__(16) short Wh[3][64 * 32], Wl[3][64 * 32];
  const int tid = threadIdx.x;
  const int w = tid >> 6, lane = tid & 63;
  const int l15 = lane & 15, quad = lane >> 4;
  const int n0 = blockIdx.y * 64, m0 = blockIdx.x * 64;

  const int row = tid >> 2, cc = tid & 3;
  const int ksw = (cc ^ (row & 3)) * 8;
  const short* gAh = Ah_g + (size_t)(n0 + row) * Dd + ksw;
  const short* gAl = Al_g + (size_t)(n0 + row) * Dd + ksw;
  const short* gWh = Wh_g + (size_t)(m0 + row) * Dd + ksw;
  const short* gWl = Wl_g + (size_t)(m0 + row) * Dd + ksw;

  f32x4 acc[4];
#pragma unroll
  for (int j = 0; j < 4; ++j) acc[j] = f32x4{0.f, 0.f, 0.f, 0.f};

  const int swq = (quad ^ (l15 & 3)) * 8;

#define STAGE_NN(kv, bf) { \
  async_cp16(gAh + (kv), &Ah[bf][tid * 8]); \
  async_cp16(gAl + (kv), &Al[bf][tid * 8]); \
  async_cp16(gWh + (kv), &Wh[bf][tid * 8]); \
  async_cp16(gWl + (kv), &Wl[bf][tid * 8]); }

  STAGE_NN(0, 0);
  STAGE_NN(32, 1);
  int bi = 0;
  for (int k0 = 0; k0 < Dd; k0 += 32) {
    if (k0 + 32 < Dd) { asm volatile("s_waitcnt vmcnt(4)" ::: "memory"); }
    else              { asm volatile("s_waitcnt vmcnt(0)" ::: "memory"); }
    __builtin_amdgcn_s_barrier();
    __builtin_amdgcn_sched_barrier(0);
    if (k0 + 64 < Dd) { const int bn = (bi + 2 >= 3) ? bi - 1 : bi + 2; STAGE_NN(k0 + 64, bn); }

    bf16x8 ah, al, wh[4], wl[4];
    ah = *(const bf16x8*)&Ah[bi][(w * 16 + l15) * 32 + swq];
    al = *(const bf16x8*)&Al[bi][(w * 16 + l15) * 32 + swq];
#pragma unroll
    for (int j = 0; j < 4; ++j) {
      wh[j] = *(const bf16x8*)&Wh[bi][(j * 16 + l15) * 32 + swq];
      wl[j] = *(const bf16x8*)&Wl[bi][(j * 16 + l15) * 32 + swq];
    }
#pragma unroll
    for (int j = 0; j < 4; ++j) {
      acc[j] = __builtin_amdgcn_mfma_f32_16x16x32_bf16(ah, wh[j], acc[j], 0, 0, 0);
      acc[j] = __builtin_amdgcn_mfma_f32_16x16x32_bf16(ah, wl[j], acc[j], 0, 0, 0);
      acc[j] = __builtin_amdgcn_mfma_f32_16x16x32_bf16(al, wh[j], acc[j], 0, 0, 0);
    }
    bi = (bi == 2) ? 0 : bi + 1;
  }
#undef STAGE_NN

#pragma unroll
  for (int r = 0; r < 4; ++r) {
    float* crow = C + (size_t)(n0 + w * 16 + quad * 4 + r) * PH + m0 + l15;
#pragma unroll
    for (int j = 0; j < 4; ++j) crow[j * 16] = acc[j][r];
  }
}

// ---------------- qkv GEMM (3-buf counted-vmcnt pipeline) + fused rotary epilogue ---
// K and V are written in an XOR-swizzled tile layout so the attention kernel can
// stage them into LDS with linear global_load_lds AND read conflict-free:
//   K: element (token n, within-head d) stored at d ^ ((n&7)<<3)
//   V^T: element (d-row, token t) stored at t ^ ((d&7)<<3)
// sched_barrier(0) after the barrier is REQUIRED (see gemm_nn_split note).
__global__ __launch_bounds__(256) void gemm_qkv_fused(
    const __hip_bfloat16* __restrict__ A, const __hip_bfloat16* __restrict__ W,
    const float* __restrict__ bias, const float* __restrict__ phases,
    __hip_bfloat16* __restrict__ q_bf, __hip_bfloat16* __restrict__ k_bf,
    __hip_bfloat16* __restrict__ vt_g)
{
  __shared__ __align__(16) short As[3][128 * 32];
  __shared__ __align__(16) short Ws[3][128 * 32];
  const int tid = threadIdx.x;
  const int w = tid >> 6, lane = tid & 63;
  const int l15 = lane & 15, quad = lane >> 4;
  const int wn = w >> 1, wm = w & 1;
  const int n0 = blockIdx.y * 128, m0 = blockIdx.x * 128;

  const int row = tid >> 2, cc = tid & 3;
  const int ksw = (cc ^ (row & 3)) * 8;
  const short* gA  = (const short*)A + (size_t)(n0 + row) * Dd + ksw;
  const short* gW  = (const short*)W + (size_t)(m0 + row) * Dd + ksw;

  f32x4 acc[4][4];
#pragma unroll
  for (int i = 0; i < 4; ++i)
#pragma unroll
    for (int j = 0; j < 4; ++j) acc[i][j] = f32x4{0.f, 0.f, 0.f, 0.f};

  const int swq = (quad ^ (l15 & 3)) * 8;

#define STAGE_QKV(kv, bf) { \
  async_cp16(gA + (kv),            &As[bf][tid * 8]); \
  async_cp16(gA + 64 * Dd + (kv),  &As[bf][2048 + tid * 8]); \
  async_cp16(gW + (kv),            &Ws[bf][tid * 8]); \
  async_cp16(gW + 64 * Dd + (kv),  &Ws[bf][2048 + tid * 8]); }

  STAGE_QKV(0, 0);
  STAGE_QKV(32, 1);
  int bi = 0;
  for (int k0 = 0; k0 < Dd; k0 += 32) {
    if (k0 + 32 < Dd) { asm volatile("s_waitcnt vmcnt(4)" ::: "memory"); }
    else              { asm volatile("s_waitcnt vmcnt(0)" ::: "memory"); }
    __builtin_amdgcn_s_barrier();
    __builtin_amdgcn_sched_barrier(0);
    if (k0 + 64 < Dd) { const int bn = (bi + 2 >= 3) ? bi - 1 : bi + 2; STAGE_QKV(k0 + 64, bn); }

    bf16x8 af[4], bf[4];
#pragma unroll
    for (int i = 0; i < 4; ++i)
      af[i] = *(const bf16x8*)&As[bi][(wn * 64 + i * 16 + l15) * 32 + swq];
#pragma unroll
    for (int j = 0; j < 4; ++j)
      bf[j] = *(const bf16x8*)&Ws[bi][(wm * 64 + j * 16 + l15) * 32 + swq];
#pragma unroll
    for (int i = 0; i < 4; ++i)
#pragma unroll
      for (int j = 0; j < 4; ++j)
        acc[i][j] = __builtin_amdgcn_mfma_f32_16x16x32_bf16(af[i], bf[j], acc[i][j], 0, 0, 0);
    bi = (bi == 2) ? 0 : bi + 1;
  }
#undef STAGE_QKV

  float bv[4];
#pragma unroll
  for (int j = 0; j < 4; ++j) bv[j] = bias[m0 + wm * 64 + j * 16 + l15];

  const int region = m0 >> 10;                 // 0=q, 1=k, 2=v (block-uniform)
  const int mloc = (m0 & 1023) + wm * 64;
  const int h = mloc >> 6;

  if (region < 2) {
    __hip_bfloat16* dst = region == 0 ? q_bf : k_bf;
    const float SC = region == 0 ? 0.18033688011112042f : 1.0f;  // (1/8)*log2(e) on q
    const int dosw = (region == 1);
#pragma unroll
    for (int i = 0; i < 4; ++i)
#pragma unroll
      for (int r = 0; r < 4; ++r) {
        const int n = n0 + wn * 64 + i * 16 + quad * 4 + r;
        const int swz = dosw ? (((quad * 4 + r) & 7) << 3) : 0;   // == (n&7)<<3
        const float* phrow = phases + (size_t)n * PH + h * 32;
        __hip_bfloat16* drow = dst + (size_t)n * Dd + h * 64;
#pragma unroll
        for (int pz = 0; pz < 2; ++pz) {
          const float ph = phrow[pz * 16 + l15];
          float sn, cs;
          __sincosf(ph, &sn, &cs);
          const float a1 = acc[i][pz][r] + bv[pz];
          const float a2 = acc[i][pz + 2][r] + bv[pz + 2];
          drow[(pz * 16 + l15) ^ swz]      = __float2bfloat16((a1 * cs - a2 * sn) * SC);
          drow[(pz * 16 + 32 + l15) ^ swz] = __float2bfloat16((a1 * sn + a2 * cs) * SC);
        }
      }
  } else {
    const int bh = (n0 >> 11) * 16 + h;
    const int tokb = (n0 & 2047) + wn * 64;
    const int vsw = (l15 & 7) << 3;            // (d&7)<<3, d = j*16+l15
#pragma unroll
    for (int i = 0; i < 4; ++i)
#pragma unroll
      for (int j = 0; j < 4; ++j) {
        const uint2 o = make_uint2(
            pack2bf(acc[i][j][0] + bv[j], acc[i][j][1] + bv[j]),
            pack2bf(acc[i][j][2] + bv[j], acc[i][j][3] + bv[j]));
        const int d = j * 16 + l15;
        *(uint2*)&vt_g[(size_t)(bh * 64 + d) * Ll + tokb + ((i * 16 + quad * 4) ^ vsw)] = o;
      }
  }
}

// ---------------- out-proj GEMM: 128n x 64m tile, 3-buf counted-vmcnt pipeline ------
// 3 loads/stage -> vmcnt(3) steady-state, vmcnt(0) on the last iteration.
__global__ __launch_bounds__(256) void gemm_bt_64(
    const __hip_bfloat16* __restrict__ A, const __hip_bfloat16* __restrict__ W,
    const float* __restrict__ bias, float* __restrict__ C, int K, int M)
{
  __shared__ __align__(16) short As[3][128 * 32];
  __shared__ __align__(16) short Ws[3][64 * 32];
  const int tid = threadIdx.x;
  const int w = tid >> 6, lane = tid & 63;
  const int l15 = lane & 15, quad = lane >> 4;
  const int n0 = blockIdx.y * 128, m0 = blockIdx.x * 64;

  const int row = tid >> 2, cc = tid & 3;
  const int ksw = (cc ^ (row & 3)) * 8;
  const short* gA = (const short*)A + (size_t)(n0 + row) * K + ksw;
  const short* gW = (const short*)W + (size_t)(m0 + row) * K + ksw;

  f32x4 acc[2][4];
#pragma unroll
  for (int i = 0; i < 2; ++i)
#pragma unroll
    for (int j = 0; j < 4; ++j) acc[i][j] = f32x4{0.f, 0.f, 0.f, 0.f};

  const int swq = (quad ^ (l15 & 3)) * 8;

#define STAGE_BT(kv, bf) { \
  async_cp16(gA + (kv),           &As[bf][tid * 8]); \
  async_cp16(gA + 64 * K + (kv),  &As[bf][2048 + tid * 8]); \
  async_cp16(gW + (kv),           &Ws[bf][tid * 8]); }

  STAGE_BT(0, 0);
  STAGE_BT(32, 1);
  int bi = 0;
  for (int k0 = 0; k0 < K; k0 += 32) {
    if (k0 + 32 < K) { asm volatile("s_waitcnt vmcnt(3)" ::: "memory"); }
    else             { asm volatile("s_waitcnt vmcnt(0)" ::: "memory"); }
    __builtin_amdgcn_s_barrier();
    __builtin_amdgcn_sched_barrier(0);
    if (k0 + 64 < K) { const int bn = (bi + 2 >= 3) ? bi - 1 : bi + 2; STAGE_BT(k0 + 64, bn); }

    bf16x8 af[2], bf[4];
#pragma unroll
    for (int i = 0; i < 2; ++i)
      af[i] = *(const bf16x8*)&As[bi][(w * 32 + i * 16 + l15) * 32 + swq];
#pragma unroll
    for (int j = 0; j < 4; ++j)
      bf[j] = *(const bf16x8*)&Ws[bi][(j * 16 + l15) * 32 + swq];
#pragma unroll
    for (int i = 0; i < 2; ++i)
#pragma unroll
      for (int j = 0; j < 4; ++j)
        acc[i][j] = __builtin_amdgcn_mfma_f32_16x16x32_bf16(af[i], bf[j], acc[i][j], 0, 0, 0);
    bi = (bi == 2) ? 0 : bi + 1;
  }
#undef STAGE_BT

  float bv[4];
#pragma unroll
  for (int j = 0; j < 4; ++j) bv[j] = bias[m0 + j * 16 + l15];
#pragma unroll
  for (int i = 0; i < 2; ++i)
#pragma unroll
    for (int r = 0; r < 4; ++r) {
      float* crow = C + (size_t)(n0 + w * 32 + i * 16 + quad * 4 + r) * M + m0 + l15;
#pragma unroll
      for (int j = 0; j < 4; ++j) crow[j * 16] = acc[i][j][r] + bv[j];
    }
}

// ---------------- bf16 MFMA flash attention (split-K, pipelined QK(kt+1) ∥ exp(kt)) -
// Q-tile 128, K-tile 64, blockIdx.z selects kt half [z*16, z*16+16). Grid 1024.
// Software pipeline (T15-style): QK^T of tile kt+1 (MFMA pipe) is issued alongside
// exp2/pack of tile kt (VALU/trans pipe); PV(kt) closes each phase. K is staged
// with lookahead 2 into Kb[2], V with lookahead 1 into Vb[2]; one barrier per kt.
__global__ __launch_bounds__(256) void attn_mfma(
    const __hip_bfloat16* __restrict__ q_bf,
    const __hip_bfloat16* __restrict__ k_bf,
    const __hip_bfloat16* __restrict__ vt_g,
    __hip_bfloat16* __restrict__ o_part,   // [2][NT][Dd] bf16
    float* __restrict__ lden_g)            // [2][Bb][Hh][Ll] fp32
{
  __shared__ __align__(16) short Kb[2][4096];
  __shared__ __align__(16) short Vb[2][4096];

  const int tid = threadIdx.x;
  const int w = tid >> 6;
  const int lane = tid & 63;
  const int l15 = lane & 15;
  const int quad = lane >> 4;

  const int q0 = blockIdx.x * 128;
  const int bh = blockIdx.y;
  const int kz = blockIdx.z;
  const int b = bh >> 4, h = bh & 15;
  const int kt0 = kz * 16;

  bf16x8 qfrag[2][2];
#pragma unroll
  for (int qg = 0; qg < 2; ++qg)
#pragma unroll
    for (int kh = 0; kh < 2; ++kh) {
      const size_t qrow = (size_t)(b * Ll + q0 + w * 32 + qg * 16 + l15);
      qfrag[qg][kh] = *(const bf16x8*)(q_bf + qrow * Dd + h * 64 + kh * 32 + quad * 8);
    }

  f32x4 acc[4][2];
#pragma unroll
  for (int dt = 0; dt < 4; ++dt)
#pragma unroll
    for (int qg = 0; qg < 2; ++qg) acc[dt][qg] = f32x4{0.f, 0.f, 0.f, 0.f};
  f32x4 lden[2] = {f32x4{0.f,0.f,0.f,0.f}, f32x4{0.f,0.f,0.f,0.f}};
  const f32x4 zro = {0.f, 0.f, 0.f, 0.f};
  const short one_bf = (short)0x3F80;           // bf16 1.0
  const bf16x8 ones8 = {one_bf, one_bf, one_bf, one_bf, one_bf, one_bf, one_bf, one_bf};

  // staging: thread tid copies 16B of row (tid>>3) (+32 rows) at byte col (tid&7)*16
  const __hip_bfloat16* ksrc = k_bf + ((size_t)(b * Ll) + (tid >> 3)) * Dd + h * 64 + (tid & 7) * 8;
  const __hip_bfloat16* vsrc = vt_g + ((size_t)(bh * 64) + (tid >> 3)) * Ll + (tid & 7) * 8;
  const int ldst = tid * 8;   // shorts offset within a 4096-short plane

  // swizzled column offsets (shorts): logical col ^ ((row&7)<<3)
  const int sw = (l15 & 7) << 3;
  const int co0 = (quad * 8) ^ sw;
  const int co1 = (32 + quad * 8) ^ sw;

#define STAGE_K(t, bf) { const __hip_bfloat16* kp_ = ksrc + (size_t)(t) * 64 * Dd; \
  async_cp16(kp_, &Kb[bf][ldst]); async_cp16(kp_ + (size_t)32 * Dd, &Kb[bf][2048 + ldst]); }
#define STAGE_V(t, bf) { const __hip_bfloat16* vp_ = vsrc + (size_t)(t) * 64; \
  async_cp16(vp_, &Vb[bf][ldst]); async_cp16(vp_ + (size_t)32 * Ll, &Vb[bf][2048 + ldst]); }

  f32x4 s[4][2];

#define QK_N(Ks, n) { \
  const bf16x8 af0_ = *(const bf16x8*)&(Ks)[((n) * 16 + l15) * 64 + co0]; \
  const bf16x8 af1_ = *(const bf16x8*)&(Ks)[((n) * 16 + l15) * 64 + co1]; \
  s[n][0] = __builtin_amdgcn_mfma_f32_16x16x32_bf16(af0_, qfrag[0][0], zro, 0, 0, 0); \
  s[n][1] = __builtin_amdgcn_mfma_f32_16x16x32_bf16(af0_, qfrag[1][0], zro, 0, 0, 0); \
  s[n][0] = __builtin_amdgcn_mfma_f32_16x16x32_bf16(af1_, qfrag[0][1], s[n][0], 0, 0, 0); \
  s[n][1] = __builtin_amdgcn_mfma_f32_16x16x32_bf16(af1_, qfrag[1][1], s[n][1], 0, 0, 0); }

#define EXPPACK(v, dst) { union { float f; unsigned u; } p0_, p1_, p2_, p3_; \
  p0_.f = __builtin_amdgcn_exp2f((v)[0]); p1_.f = __builtin_amdgcn_exp2f((v)[1]); \
  p2_.f = __builtin_amdgcn_exp2f((v)[2]); p3_.f = __builtin_amdgcn_exp2f((v)[3]); \
  dst = make_uint2(__builtin_amdgcn_perm(p1_.u, p0_.u, 0x07060302u), \
                   __builtin_amdgcn_perm(p3_.u, p2_.u, 0x07060302u)); }

#define PV_QG(va, aU, cU, qg) { \
  auto rx32_ = __builtin_amdgcn_permlane32_swap((aU).x, (cU).x, false, false); \
  auto rx16_ = __builtin_amdgcn_permlane16_swap(rx32_[0], rx32_[1], false, false); \
  auto ry32_ = __builtin_amdgcn_permlane32_swap((aU).y, (cU).y, false, false); \
  auto ry16_ = __builtin_amdgcn_permlane16_swap(ry32_[0], ry32_[1], false, false); \
  union { unsigned u[4]; bf16x8 v; } pb_; \
  pb_.u[0] = rx16_[0]; pb_.u[1] = ry16_[0]; pb_.u[2] = rx16_[1]; pb_.u[3] = ry16_[1]; \
  lden[qg] = __builtin_amdgcn_mfma_f32_16x16x32_bf16(ones8, pb_.v, lden[qg], 0, 0, 0); \
  acc[0][qg] = __builtin_amdgcn_mfma_f32_16x16x32_bf16(va[0], pb_.v, acc[0][qg], 0, 0, 0); \
  acc[1][qg] = __builtin_amdgcn_mfma_f32_16x16x32_bf16(va[1], pb_.v, acc[1][qg], 0, 0, 0); \
  acc[2][qg] = __builtin_amdgcn_mfma_f32_16x16x32_bf16(va[2], pb_.v, acc[2][qg], 0, 0, 0); \
  acc[3][qg] = __builtin_amdgcn_mfma_f32_16x16x32_bf16(va[3], pb_.v, acc[3][qg], 0, 0, 0); }

  // prologue: K(0) -> Kb[0]; after barrier, start K(1),V(0) and compute QK(0)
  STAGE_K(kt0, 0);
  __syncthreads();
  STAGE_K(kt0 + 1, 1);
  STAGE_V(kt0, 0);
  __builtin_amdgcn_s_setprio(1);
  QK_N(Kb[0], 0); QK_N(Kb[0], 1); QK_N(Kb[0], 2); QK_N(Kb[0], 3);
  __builtin_amdgcn_s_setprio(0);

  for (int i = 0; i < 16; ++i) {
    __syncthreads();   // implicit vmcnt(0): K(i+1),V(i) staged; all prev reads done
    if (i + 2 < 16) STAGE_K(kt0 + i + 2, i & 1);
    if (i + 1 < 16) STAGE_V(kt0 + i + 1, (i + 1) & 1);
    const short* Kn = &Kb[(i + 1) & 1][0];
    const short* Vc = &Vb[i & 1][0];
    const bool doqk = (i + 1 < 16);

    // ---- phase 0: exp/pack P rows 0..31 ∥ QK(i+1) rows 0..31, then PV pr=0 ----
    uint2 a0, a1, c0, c1;
    EXPPACK(s[0][0], a0); EXPPACK(s[0][1], a1);
    EXPPACK(s[1][0], c0); EXPPACK(s[1][1], c1);
    if (doqk) {
      __builtin_amdgcn_s_setprio(1);
      QK_N(Kn, 0); QK_N(Kn, 1);
      __builtin_amdgcn_s_setprio(0);
    }
    {
      bf16x8 va[4];
#pragma unroll
      for (int dt = 0; dt < 4; ++dt)
        va[dt] = *(const bf16x8*)&Vc[(dt * 16 + l15) * 64 + co0];
      __builtin_amdgcn_s_setprio(1);
      PV_QG(va, a0, c0, 0);
      PV_QG(va, a1, c1, 1);
      __builtin_amdgcn_s_setprio(0);
    }

    // ---- phase 1: exp/pack P rows 32..63 ∥ QK(i+1) rows 32..63, then PV pr=1 ----
    uint2 a2, a3, c2, c3;
    EXPPACK(s[2][0], a2); EXPPACK(s[2][1], a3);
    EXPPACK(s[3][0], c2); EXPPACK(s[3][1], c3);
    if (doqk) {
      __builtin_amdgcn_s_setprio(1);
      QK_N(Kn, 2); QK_N(Kn, 3);
      __builtin_amdgcn_s_setprio(0);
    }
    {
      bf16x8 va[4];
#pragma unroll
      for (int dt = 0; dt < 4; ++dt)
        va[dt] = *(const bf16x8*)&Vc[(dt * 16 + l15) * 64 + co1];
      __builtin_amdgcn_s_setprio(1);
      PV_QG(va, a2, c2, 0);
      PV_QG(va, a3, c3, 1);
      __builtin_amdgcn_s_setprio(0);
    }
  }

#undef STAGE_K
#undef STAGE_V
#undef QK_N
#undef EXPPACK
#undef PV_QG

#pragma unroll
  for (int qg = 0; qg < 2; ++qg) {
    const float lv = lden[qg][0];           // all rows identical; col l15 = this q
    const float linv = 1.f / lv;
    const int ql = q0 + w * 32 + qg * 16 + l15;
    if (quad == 0)
      lden_g[((size_t)(kz * Bb + b) * Hh + h) * Ll + ql] = lv;
    __hip_bfloat16* dst = o_part + ((size_t)kz * NT + b * Ll + ql) * Dd + h * 64;
#pragma unroll
    for (int dt = 0; dt < 4; ++dt) {
      const uint2 o = make_uint2(
          pack2bf(acc[dt][qg][0] * linv, acc[dt][qg][1] * linv),
          pack2bf(acc[dt][qg][2] * linv, acc[dt][qg][3] * linv));
      *(uint2*)&dst[dt * 16 + quad * 4] = o;
    }
  }
}

// ---------------- combine the two split-K partials -----------------------------------
// aout[n][d] = (l0*O0 + l1*O1) / (l0+l1); one thread per 4 d.
__global__ __launch_bounds__(256) void attn_combine(
    const __hip_bfloat16* __restrict__ o_part, const float* __restrict__ lden_g,
    __hip_bfloat16* __restrict__ aout)
{
  const int i = blockIdx.x * 256 + threadIdx.x;   // NT*Dd/4 = 1,048,576
  const int n = i >> 8, d4 = i & 255;
  const int b = n >> 11, l = n & 2047;
  const int h = d4 >> 4;
  const float l0 = lden_g[((size_t)b * Hh + h) * Ll + l];
  const float l1 = lden_g[((size_t)(Bb + b) * Hh + h) * Ll + l];
  const float inv = 1.f / (l0 + l1);
  const float w0 = l0 * inv, w1 = l1 * inv;
  const uint2 a0 = ((const uint2*)o_part)[i];
  const uint2 a1 = ((const uint2*)o_part)[(NT * (size_t)Dd / 4) + i];
  const float r0 = w0 * bfhalf(a0.x, 0) + w1 * bfhalf(a1.x, 0);
  const float r1 = w0 * bfhalf(a0.x, 1) + w1 * bfhalf(a1.x, 1);
  const float r2 = w0 * bfhalf(a0.y, 0) + w1 * bfhalf(a1.y, 0);
  const float r3 = w0 * bfhalf(a0.y, 1) + w1 * bfhalf(a1.y, 1);
  ((uint2*)aout)[i] = make_uint2(pack2bf(r0, r1), pack2bf(r2, r3));
}

extern "C" void kernel_launch(void* const* d_in, const int* in_sizes, int n_in,
                              void* d_out, int out_size, void* d_ws, size_t ws_size,
                              hipStream_t stream) {
  const float* x     = (const float*)d_in[0];
  const float* p     = (const float*)d_in[1];
  const float* W_qkv = (const float*)d_in[2];
  const float* b_qkv = (const float*)d_in[3];
  const float* W_out = (const float*)d_in[4];
  const float* b_out = (const float*)d_in[5];
  const float* proj  = (const float*)d_in[6];
  float* out = (float*)d_out;

  // workspace overlay (~61 MiB):
  //  [0,8Mi):   phases fp32
  //  [8,16Mi):  p_hi  -> (dead after phases gemm) aout_bf
  //  [16,24Mi): p_lo  -> (dead after phases gemm) vt_g
  //  [24,25Mi): projt_hi   [25,26Mi): projt_lo
  //  [26,34Mi): q_bf   [34,42Mi): k_bf
  //  [42,50Mi): x_bf     -> (dead after qkv gemm) o_part z0
  //  [50,56Mi): wqkv_bf  -> (dead after qkv gemm) o_part z1 [50,58Mi)
  //  [58,60Mi): wout_bf
  //  [60,60.5Mi): lden_g
  char* wsb = (char*)d_ws;
  float*          phases   = (float*)(wsb);
  short*          p_hi     = (short*)(wsb + (8u << 20));
  __hip_bfloat16* aout_bf  = (__hip_bfloat16*)(wsb + (8u << 20));
  short*          p_lo     = (short*)(wsb + (16u << 20));
  __hip_bfloat16* vt_g     = (__hip_bfloat16*)(wsb + (16u << 20));
  short*          projt_hi = (short*)(wsb + (24u << 20));
  short*          projt_lo = (short*)(wsb + (25u << 20));
  __hip_bfloat16* q_bf     = (__hip_bfloat16*)(wsb + (26u << 20));
  __hip_bfloat16* k_bf     = (__hip_bfloat16*)(wsb + (34u << 20));
  __hip_bfloat16* x_bf     = (__hip_bfloat16*)(wsb + (42u << 20));
  __hip_bfloat16* o_part   = (__hip_bfloat16*)(wsb + (42u << 20));
  __hip_bfloat16* wqkv_bf  = (__hip_bfloat16*)(wsb + (50u << 20));
  __hip_bfloat16* wout_bf  = (__hip_bfloat16*)(wsb + (58u << 20));
  float*          lden_g   = (float*)(wsb + (60u << 20));

  // merged input prep
  prep_kernel<<<12416, 256, 0, stream>>>(
      (const float4*)p, (uint2*)p_hi, (uint2*)p_lo,
      proj, projt_hi, projt_lo,
      (const float4*)x, (const float4*)W_qkv, (const float4*)W_out,
      (uint2*)x_bf, (uint2*)wqkv_bf, (uint2*)wout_bf);
  // phases = p @ proj (split-bf16), 64x64 tiles -> 512 blocks (2/CU)
  gemm_nn_split<<<dim3(PH / 64, NT / 64), 256, 0, stream>>>(p_hi, p_lo, projt_hi, projt_lo, phases);
  // qkv GEMM + fused rotary/cast/swizzled V/K epilogue
  gemm_qkv_fused<<<dim3(D3 / 128, NT / 128), 256, 0, stream>>>(x_bf, wqkv_bf, b_qkv, phases,
                                                               q_bf, k_bf, vt_g);
  // flash attention (split-K halves, pipelined) -> partials
  attn_mfma<<<dim3(Ll / 128, Bb * Hh, 2), 256, 0, stream>>>(q_bf, k_bf, vt_g, o_part, lden_g);
  // combine partials -> aout bf16
  attn_combine<<<4096, 256, 0, stream>>>(o_part, lden_g, aout_bf);
  // out = aout @ W_out^T + b_out (128n x 64m tiles, 512 blocks)
  gemm_bt_64<<<dim3(Dd / 64, NT / 128), 256, 0, stream>>>(aout_bf, wout_bf, b_out, out, Dd, Dd);
}

// Round 13
// 250.477 us; speedup vs baseline: 1.0495x; 1.0162x over previous
//
#include <hip/hip_runtime.h>
#include <hip/hip_bf16.h>
#include <math.h>

namespace {
constexpr int Bb = 2;
constexpr int Ll = 2048;
constexpr int Dd = 1024;
constexpr int Hh = 16;
constexpr int NT = Bb * Ll;   // 4096 tokens
constexpr int D3 = 3 * Dd;    // 3072
constexpr int PH = Dd / 2;    // 512 phases per token
}

typedef __attribute__((ext_vector_type(8))) short bf16x8;
typedef __attribute__((ext_vector_type(4))) float f32x4;

__device__ inline unsigned pack2bf(float a, float b) {
  __hip_bfloat162 t = __float22bfloat162_rn(float2{a, b});
  union { __hip_bfloat162 h; unsigned u; } cv; cv.h = t;
  return cv.u;
}

__device__ inline float bfhalf(unsigned u, int hi) {
  union { unsigned u; float f; } c;
  c.u = hi ? (u & 0xffff0000u) : (u << 16);
  return c.f;
}

__device__ inline void async_cp16(const void* gsrc, void* ldst) {
  __builtin_amdgcn_global_load_lds(
      (const __attribute__((address_space(1))) unsigned int*)gsrc,
      (__attribute__((address_space(3))) unsigned int*)ldst, 16, 0, 0);
}

// ---------------- merged input prep: split_cast(p) + trans_split(proj) + cast3 ------
__global__ __launch_bounds__(256) void prep_kernel(
    const float4* __restrict__ p, uint2* __restrict__ p_hi4, uint2* __restrict__ p_lo4,
    const float* __restrict__ proj, short* __restrict__ th, short* __restrict__ tl,
    const float4* __restrict__ x, const float4* __restrict__ wq, const float4* __restrict__ wo,
    uint2* __restrict__ xd, uint2* __restrict__ wqd, uint2* __restrict__ wod)
{
  __shared__ float Ls[64][65];
  const int bid = blockIdx.x;
  const int tid = threadIdx.x;

  if (bid < 4096) {
    const int i = bid * 256 + tid;
    const float4 f = p[i];
    float hf[4], lf[4];
    const float ff[4] = {f.x, f.y, f.z, f.w};
#pragma unroll
    for (int j = 0; j < 4; ++j) {
      const __hip_bfloat16 h = __float2bfloat16(ff[j]);
      hf[j] = __bfloat162float(h);
      lf[j] = ff[j] - hf[j];
    }
    p_hi4[i] = make_uint2(pack2bf(hf[0], hf[1]), pack2bf(hf[2], hf[3]));
    p_lo4[i] = make_uint2(pack2bf(lf[0], lf[1]), pack2bf(lf[2], lf[3]));
  } else if (bid < 4224) {
    const int bx = bid - 4096;
    const int d0 = (bx & 15) * 64, m0 = (bx >> 4) * 64;
    const int r = tid >> 4, c4 = (tid & 15) * 4;
#pragma unroll
    for (int it = 0; it < 4; ++it) {
      const int row = it * 16 + r;
      const float4 v = *(const float4*)&proj[(size_t)(d0 + row) * PH + m0 + c4];
      Ls[row][c4] = v.x; Ls[row][c4+1] = v.y; Ls[row][c4+2] = v.z; Ls[row][c4+3] = v.w;
    }
    __syncthreads();
#pragma unroll
    for (int it = 0; it < 4; ++it) {
      const int row = it * 16 + r;
      float hf[4], lf[4];
#pragma unroll
      for (int j = 0; j < 4; ++j) {
        const float v = Ls[c4 + j][row];
        const __hip_bfloat16 h = __float2bfloat16(v);
        hf[j] = __bfloat162float(h);
        lf[j] = v - hf[j];
      }
      *(uint2*)&th[(size_t)(m0 + row) * Dd + d0 + c4] = make_uint2(pack2bf(hf[0], hf[1]), pack2bf(hf[2], hf[3]));
      *(uint2*)&tl[(size_t)(m0 + row) * Dd + d0 + c4] = make_uint2(pack2bf(lf[0], lf[1]), pack2bf(lf[2], lf[3]));
    }
  } else {
    int i = (bid - 4224) * 256 + tid;   // covers 2,097,152
    const float4* s; uint2* d;
    if (i < 1048576) { s = x; d = xd; }
    else if (i < 1048576 + 786432) { i -= 1048576; s = wq; d = wqd; }
    else { i -= 1048576 + 786432; s = wo; d = wod; }
    const float4 f = s[i];
    d[i] = make_uint2(pack2bf(f.x, f.y), pack2bf(f.z, f.w));
  }
}

// ---------------- split-bf16 MFMA GEMM for phases: 64n x 64m tile ------------------
// 3-buffer LDS pipeline, lookahead-2, counted vmcnt (4 loads/stage). The
// sched_barrier(0) after the barrier is REQUIRED: without it the compiler
// re-interleaves stage-issues/ds_reads around the hand-counted vmcnt (R7: -10us).
__global__ __launch_bounds__(256) void gemm_nn_split(
    const short* __restrict__ Ah_g, const short* __restrict__ Al_g,
    const short* __restrict__ Wh_g, const short* __restrict__ Wl_g,
    float* __restrict__ C)
{
  __shared__ __align__(16) short Ah[3][64 * 32], Al[3][64 * 32];
  __shared__ __align__(16) short Wh[3][64 * 32], Wl[3][64 * 32];
  const int tid = threadIdx.x;
  const int w = tid >> 6, lane = tid & 63;
  const int l15 = lane & 15, quad = lane >> 4;
  const int n0 = blockIdx.y * 64, m0 = blockIdx.x * 64;

  const int row = tid >> 2, cc = tid & 3;
  const int ksw = (cc ^ (row & 3)) * 8;
  const short* gAh = Ah_g + (size_t)(n0 + row) * Dd + ksw;
  const short* gAl = Al_g + (size_t)(n0 + row) * Dd + ksw;
  const short* gWh = Wh_g + (size_t)(m0 + row) * Dd + ksw;
  const short* gWl = Wl_g + (size_t)(m0 + row) * Dd + ksw;

  f32x4 acc[4];
#pragma unroll
  for (int j = 0; j < 4; ++j) acc[j] = f32x4{0.f, 0.f, 0.f, 0.f};

  const int swq = (quad ^ (l15 & 3)) * 8;

#define STAGE_NN(kv, bf) { \
  async_cp16(gAh + (kv), &Ah[bf][tid * 8]); \
  async_cp16(gAl + (kv), &Al[bf][tid * 8]); \
  async_cp16(gWh + (kv), &Wh[bf][tid * 8]); \
  async_cp16(gWl + (kv), &Wl[bf][tid * 8]); }

  STAGE_NN(0, 0);
  STAGE_NN(32, 1);
  int bi = 0;
  for (int k0 = 0; k0 < Dd; k0 += 32) {
    if (k0 + 32 < Dd) { asm volatile("s_waitcnt vmcnt(4)" ::: "memory"); }
    else              { asm volatile("s_waitcnt vmcnt(0)" ::: "memory"); }
    __builtin_amdgcn_s_barrier();
    __builtin_amdgcn_sched_barrier(0);
    if (k0 + 64 < Dd) { const int bn = (bi + 2 >= 3) ? bi - 1 : bi + 2; STAGE_NN(k0 + 64, bn); }

    bf16x8 ah, al, wh[4], wl[4];
    ah = *(const bf16x8*)&Ah[bi][(w * 16 + l15) * 32 + swq];
    al = *(const bf16x8*)&Al[bi][(w * 16 + l15) * 32 + swq];
#pragma unroll
    for (int j = 0; j < 4; ++j) {
      wh[j] = *(const bf16x8*)&Wh[bi][(j * 16 + l15) * 32 + swq];
      wl[j] = *(const bf16x8*)&Wl[bi][(j * 16 + l15) * 32 + swq];
    }
#pragma unroll
    for (int j = 0; j < 4; ++j) {
      acc[j] = __builtin_amdgcn_mfma_f32_16x16x32_bf16(ah, wh[j], acc[j], 0, 0, 0);
      acc[j] = __builtin_amdgcn_mfma_f32_16x16x32_bf16(ah, wl[j], acc[j], 0, 0, 0);
      acc[j] = __builtin_amdgcn_mfma_f32_16x16x32_bf16(al, wh[j], acc[j], 0, 0, 0);
    }
    bi = (bi == 2) ? 0 : bi + 1;
  }
#undef STAGE_NN

#pragma unroll
  for (int r = 0; r < 4; ++r) {
    float* crow = C + (size_t)(n0 + w * 16 + quad * 4 + r) * PH + m0 + l15;
#pragma unroll
    for (int j = 0; j < 4; ++j) crow[j * 16] = acc[j][r];
  }
}

// ---------------- qkv GEMM: 128n x 64m tile (1536 blocks, 4/CU resident) ------------
// Retiled from 128x128 (R13): LDS 48->36KB lifts residency 3->4 blocks/CU (+33%
// waves to fill latency). m-tile = exactly one head -> simpler rotary epilogue.
// 3-buffer pipeline, lookahead-2, counted vmcnt(3); sched_barrier(0) REQUIRED.
// K and V written in the XOR-swizzled layout the attention kernel expects:
//   K: element (token n, within-head d) stored at d ^ ((n&7)<<3)
//   V^T: element (d-row, token t) stored at (t within 64-group) ^ ((d&7)<<3)
__global__ __launch_bounds__(256) void gemm_qkv_fused(
    const __hip_bfloat16* __restrict__ A, const __hip_bfloat16* __restrict__ W,
    const float* __restrict__ bias, const float* __restrict__ phases,
    __hip_bfloat16* __restrict__ q_bf, __hip_bfloat16* __restrict__ k_bf,
    __hip_bfloat16* __restrict__ vt_g)
{
  __shared__ __align__(16) short As[3][128 * 32];
  __shared__ __align__(16) short Ws[3][64 * 32];
  const int tid = threadIdx.x;
  const int w = tid >> 6, lane = tid & 63;
  const int l15 = lane & 15, quad = lane >> 4;
  const int n0 = blockIdx.y * 128, m0 = blockIdx.x * 64;

  const int row = tid >> 2, cc = tid & 3;
  const int ksw = (cc ^ (row & 3)) * 8;
  const short* gA = (const short*)A + (size_t)(n0 + row) * Dd + ksw;
  const short* gW = (const short*)W + (size_t)(m0 + row) * Dd + ksw;

  f32x4 acc[2][4];
#pragma unroll
  for (int i = 0; i < 2; ++i)
#pragma unroll
    for (int j = 0; j < 4; ++j) acc[i][j] = f32x4{0.f, 0.f, 0.f, 0.f};

  const int swq = (quad ^ (l15 & 3)) * 8;

#define STAGE_QKV(kv, bf) { \
  async_cp16(gA + (kv),            &As[bf][tid * 8]); \
  async_cp16(gA + 64 * Dd + (kv),  &As[bf][2048 + tid * 8]); \
  async_cp16(gW + (kv),            &Ws[bf][tid * 8]); }

  STAGE_QKV(0, 0);
  STAGE_QKV(32, 1);
  int bi = 0;
  for (int k0 = 0; k0 < Dd; k0 += 32) {
    if (k0 + 32 < Dd) { asm volatile("s_waitcnt vmcnt(3)" ::: "memory"); }
    else              { asm volatile("s_waitcnt vmcnt(0)" ::: "memory"); }
    __builtin_amdgcn_s_barrier();
    __builtin_amdgcn_sched_barrier(0);
    if (k0 + 64 < Dd) { const int bn = (bi + 2 >= 3) ? bi - 1 : bi + 2; STAGE_QKV(k0 + 64, bn); }

    bf16x8 af[2], bf[4];
#pragma unroll
    for (int i = 0; i < 2; ++i)
      af[i] = *(const bf16x8*)&As[bi][(w * 32 + i * 16 + l15) * 32 + swq];
#pragma unroll
    for (int j = 0; j < 4; ++j)
      bf[j] = *(const bf16x8*)&Ws[bi][(j * 16 + l15) * 32 + swq];
#pragma unroll
    for (int i = 0; i < 2; ++i)
#pragma unroll
      for (int j = 0; j < 4; ++j)
        acc[i][j] = __builtin_amdgcn_mfma_f32_16x16x32_bf16(af[i], bf[j], acc[i][j], 0, 0, 0);
    bi = (bi == 2) ? 0 : bi + 1;
  }
#undef STAGE_QKV

  float bv[4];
#pragma unroll
  for (int j = 0; j < 4; ++j) bv[j] = bias[m0 + j * 16 + l15];

  const int region = m0 >> 10;                 // 0=q, 1=k, 2=v (block-uniform)
  const int h = (m0 & 1023) >> 6;              // m-tile is exactly one head

  if (region < 2) {
    __hip_bfloat16* dst = region == 0 ? q_bf : k_bf;
    const float SC = region == 0 ? 0.18033688011112042f : 1.0f;  // (1/8)*log2(e) on q
    const int dosw = (region == 1);
#pragma unroll
    for (int i = 0; i < 2; ++i)
#pragma unroll
      for (int r = 0; r < 4; ++r) {
        const int n = n0 + w * 32 + i * 16 + quad * 4 + r;
        const int swz = dosw ? (((quad * 4 + r) & 7) << 3) : 0;   // == (n&7)<<3
        const float* phrow = phases + (size_t)n * PH + h * 32;
        __hip_bfloat16* drow = dst + (size_t)n * Dd + h * 64;
#pragma unroll
        for (int pz = 0; pz < 2; ++pz) {
          const float ph = phrow[pz * 16 + l15];
          float sn, cs;
          __sincosf(ph, &sn, &cs);
          const float a1 = acc[i][pz][r] + bv[pz];
          const float a2 = acc[i][pz + 2][r] + bv[pz + 2];
          drow[(pz * 16 + l15) ^ swz]      = __float2bfloat16((a1 * cs - a2 * sn) * SC);
          drow[(pz * 16 + 32 + l15) ^ swz] = __float2bfloat16((a1 * sn + a2 * cs) * SC);
        }
      }
  } else {
    const int bh = (n0 >> 11) * 16 + h;
    const int tokb = (n0 & 2047) + (w >> 1) * 64;     // 64-token group base
    const int loc0 = (w & 1) * 32;                    // token-local base within group
    const int vsw = (l15 & 7) << 3;                   // (d&7)<<3, d = j*16+l15
#pragma unroll
    for (int i = 0; i < 2; ++i)
#pragma unroll
      for (int j = 0; j < 4; ++j) {
        const uint2 o = make_uint2(
            pack2bf(acc[i][j][0] + bv[j], acc[i][j][1] + bv[j]),
            pack2bf(acc[i][j][2] + bv[j], acc[i][j][3] + bv[j]));
        const int d = j * 16 + l15;
        *(uint2*)&vt_g[(size_t)(bh * 64 + d) * Ll + tokb + ((loc0 + i * 16 + quad * 4) ^ vsw)] = o;
      }
  }
}

// ---------------- out-proj GEMM: 128n x 64m tile, 3-buf counted-vmcnt pipeline ------
// 3 loads/stage -> vmcnt(3) steady-state, vmcnt(0) on the last iteration.
__global__ __launch_bounds__(256) void gemm_bt_64(
    const __hip_bfloat16* __restrict__ A, const __hip_bfloat16* __restrict__ W,
    const float* __restrict__ bias, float* __restrict__ C, int K, int M)
{
  __shared__ __align__(16) short As[3][128 * 32];
  __shared__ __align__(16) short Ws[3][64 * 32];
  const int tid = threadIdx.x;
  const int w = tid >> 6, lane = tid & 63;
  const int l15 = lane & 15, quad = lane >> 4;
  const int n0 = blockIdx.y * 128, m0 = blockIdx.x * 64;

  const int row = tid >> 2, cc = tid & 3;
  const int ksw = (cc ^ (row & 3)) * 8;
  const short* gA = (const short*)A + (size_t)(n0 + row) * K + ksw;
  const short* gW = (const short*)W + (size_t)(m0 + row) * K + ksw;

  f32x4 acc[2][4];
#pragma unroll
  for (int i = 0; i < 2; ++i)
#pragma unroll
    for (int j = 0; j < 4; ++j) acc[i][j] = f32x4{0.f, 0.f, 0.f, 0.f};

  const int swq = (quad ^ (l15 & 3)) * 8;

#define STAGE_BT(kv, bf) { \
  async_cp16(gA + (kv),           &As[bf][tid * 8]); \
  async_cp16(gA + 64 * K + (kv),  &As[bf][2048 + tid * 8]); \
  async_cp16(gW + (kv),           &Ws[bf][tid * 8]); }

  STAGE_BT(0, 0);
  STAGE_BT(32, 1);
  int bi = 0;
  for (int k0 = 0; k0 < K; k0 += 32) {
    if (k0 + 32 < K) { asm volatile("s_waitcnt vmcnt(3)" ::: "memory"); }
    else             { asm volatile("s_waitcnt vmcnt(0)" ::: "memory"); }
    __builtin_amdgcn_s_barrier();
    __builtin_amdgcn_sched_barrier(0);
    if (k0 + 64 < K) { const int bn = (bi + 2 >= 3) ? bi - 1 : bi + 2; STAGE_BT(k0 + 64, bn); }

    bf16x8 af[2], bf[4];
#pragma unroll
    for (int i = 0; i < 2; ++i)
      af[i] = *(const bf16x8*)&As[bi][(w * 32 + i * 16 + l15) * 32 + swq];
#pragma unroll
    for (int j = 0; j < 4; ++j)
      bf[j] = *(const bf16x8*)&Ws[bi][(j * 16 + l15) * 32 + swq];
#pragma unroll
    for (int i = 0; i < 2; ++i)
#pragma unroll
      for (int j = 0; j < 4; ++j)
        acc[i][j] = __builtin_amdgcn_mfma_f32_16x16x32_bf16(af[i], bf[j], acc[i][j], 0, 0, 0);
    bi = (bi == 2) ? 0 : bi + 1;
  }
#undef STAGE_BT

  float bv[4];
#pragma unroll
  for (int j = 0; j < 4; ++j) bv[j] = bias[m0 + j * 16 + l15];
#pragma unroll
  for (int i = 0; i < 2; ++i)
#pragma unroll
    for (int r = 0; r < 4; ++r) {
      float* crow = C + (size_t)(n0 + w * 32 + i * 16 + quad * 4 + r) * M + m0 + l15;
#pragma unroll
      for (int j = 0; j < 4; ++j) crow[j * 16] = acc[i][j][r] + bv[j];
    }
}

// ---------------- bf16 MFMA flash attention (split-K, pipelined QK(kt+1) ∥ exp(kt)) -
// Q-tile 128, K-tile 64, blockIdx.z selects kt half [z*16, z*16+16). Grid 1024.
// Software pipeline (T15-style): QK^T of tile kt+1 (MFMA pipe) is issued alongside
// exp2/pack of tile kt (VALU/trans pipe); PV(kt) closes each phase. K is staged
// with lookahead 2 into Kb[2], V with lookahead 1 into Vb[2]; one barrier per kt.
__global__ __launch_bounds__(256) void attn_mfma(
    const __hip_bfloat16* __restrict__ q_bf,
    const __hip_bfloat16* __restrict__ k_bf,
    const __hip_bfloat16* __restrict__ vt_g,
    __hip_bfloat16* __restrict__ o_part,   // [2][NT][Dd] bf16
    float* __restrict__ lden_g)            // [2][Bb][Hh][Ll] fp32
{
  __shared__ __align__(16) short Kb[2][4096];
  __shared__ __align__(16) short Vb[2][4096];

  const int tid = threadIdx.x;
  const int w = tid >> 6;
  const int lane = tid & 63;
  const int l15 = lane & 15;
  const int quad = lane >> 4;

  const int q0 = blockIdx.x * 128;
  const int bh = blockIdx.y;
  const int kz = blockIdx.z;
  const int b = bh >> 4, h = bh & 15;
  const int kt0 = kz * 16;

  bf16x8 qfrag[2][2];
#pragma unroll
  for (int qg = 0; qg < 2; ++qg)
#pragma unroll
    for (int kh = 0; kh < 2; ++kh) {
      const size_t qrow = (size_t)(b * Ll + q0 + w * 32 + qg * 16 + l15);
      qfrag[qg][kh] = *(const bf16x8*)(q_bf + qrow * Dd + h * 64 + kh * 32 + quad * 8);
    }

  f32x4 acc[4][2];
#pragma unroll
  for (int dt = 0; dt < 4; ++dt)
#pragma unroll
    for (int qg = 0; qg < 2; ++qg) acc[dt][qg] = f32x4{0.f, 0.f, 0.f, 0.f};
  f32x4 lden[2] = {f32x4{0.f,0.f,0.f,0.f}, f32x4{0.f,0.f,0.f,0.f}};
  const f32x4 zro = {0.f, 0.f, 0.f, 0.f};
  const short one_bf = (short)0x3F80;           // bf16 1.0
  const bf16x8 ones8 = {one_bf, one_bf, one_bf, one_bf, one_bf, one_bf, one_bf, one_bf};

  // staging: thread tid copies 16B of row (tid>>3) (+32 rows) at byte col (tid&7)*16
  const __hip_bfloat16* ksrc = k_bf + ((size_t)(b * Ll) + (tid >> 3)) * Dd + h * 64 + (tid & 7) * 8;
  const __hip_bfloat16* vsrc = vt_g + ((size_t)(bh * 64) + (tid >> 3)) * Ll + (tid & 7) * 8;
  const int ldst = tid * 8;   // shorts offset within a 4096-short plane

  // swizzled column offsets (shorts): logical col ^ ((row&7)<<3)
  const int sw = (l15 & 7) << 3;
  const int co0 = (quad * 8) ^ sw;
  const int co1 = (32 + quad * 8) ^ sw;

#define STAGE_K(t, bf) { const __hip_bfloat16* kp_ = ksrc + (size_t)(t) * 64 * Dd; \
  async_cp16(kp_, &Kb[bf][ldst]); async_cp16(kp_ + (size_t)32 * Dd, &Kb[bf][2048 + ldst]); }
#define STAGE_V(t, bf) { const __hip_bfloat16* vp_ = vsrc + (size_t)(t) * 64; \
  async_cp16(vp_, &Vb[bf][ldst]); async_cp16(vp_ + (size_t)32 * Ll, &Vb[bf][2048 + ldst]); }

  f32x4 s[4][2];

#define QK_N(Ks, n) { \
  const bf16x8 af0_ = *(const bf16x8*)&(Ks)[((n) * 16 + l15) * 64 + co0]; \
  const bf16x8 af1_ = *(const bf16x8*)&(Ks)[((n) * 16 + l15) * 64 + co1]; \
  s[n][0] = __builtin_amdgcn_mfma_f32_16x16x32_bf16(af0_, qfrag[0][0], zro, 0, 0, 0); \
  s[n][1] = __builtin_amdgcn_mfma_f32_16x16x32_bf16(af0_, qfrag[1][0], zro, 0, 0, 0); \
  s[n][0] = __builtin_amdgcn_mfma_f32_16x16x32_bf16(af1_, qfrag[0][1], s[n][0], 0, 0, 0); \
  s[n][1] = __builtin_amdgcn_mfma_f32_16x16x32_bf16(af1_, qfrag[1][1], s[n][1], 0, 0, 0); }

#define EXPPACK(v, dst) { union { float f; unsigned u; } p0_, p1_, p2_, p3_; \
  p0_.f = __builtin_amdgcn_exp2f((v)[0]); p1_.f = __builtin_amdgcn_exp2f((v)[1]); \
  p2_.f = __builtin_amdgcn_exp2f((v)[2]); p3_.f = __builtin_amdgcn_exp2f((v)[3]); \
  dst = make_uint2(__builtin_amdgcn_perm(p1_.u, p0_.u, 0x07060302u), \
                   __builtin_amdgcn_perm(p3_.u, p2_.u, 0x07060302u)); }

#define PV_QG(va, aU, cU, qg) { \
  auto rx32_ = __builtin_amdgcn_permlane32_swap((aU).x, (cU).x, false, false); \
  auto rx16_ = __builtin_amdgcn_permlane16_swap(rx32_[0], rx32_[1], false, false); \
  auto ry32_ = __builtin_amdgcn_permlane32_swap((aU).y, (cU).y, false, false); \
  auto ry16_ = __builtin_amdgcn_permlane16_swap(ry32_[0], ry32_[1], false, false); \
  union { unsigned u[4]; bf16x8 v; } pb_; \
  pb_.u[0] = rx16_[0]; pb_.u[1] = ry16_[0]; pb_.u[2] = rx16_[1]; pb_.u[3] = ry16_[1]; \
  lden[qg] = __builtin_amdgcn_mfma_f32_16x16x32_bf16(ones8, pb_.v, lden[qg], 0, 0, 0); \
  acc[0][qg] = __builtin_amdgcn_mfma_f32_16x16x32_bf16(va[0], pb_.v, acc[0][qg], 0, 0, 0); \
  acc[1][qg] = __builtin_amdgcn_mfma_f32_16x16x32_bf16(va[1], pb_.v, acc[1][qg], 0, 0, 0); \
  acc[2][qg] = __builtin_amdgcn_mfma_f32_16x16x32_bf16(va[2], pb_.v, acc[2][qg], 0, 0, 0); \
  acc[3][qg] = __builtin_amdgcn_mfma_f32_16x16x32_bf16(va[3], pb_.v, acc[3][qg], 0, 0, 0); }

  // prologue: K(0) -> Kb[0]; after barrier, start K(1),V(0) and compute QK(0)
  STAGE_K(kt0, 0);
  __syncthreads();
  STAGE_K(kt0 + 1, 1);
  STAGE_V(kt0, 0);
  __builtin_amdgcn_s_setprio(1);
  QK_N(Kb[0], 0); QK_N(Kb[0], 1); QK_N(Kb[0], 2); QK_N(Kb[0], 3);
  __builtin_amdgcn_s_setprio(0);

  for (int i = 0; i < 16; ++i) {
    __syncthreads();   // implicit vmcnt(0): K(i+1),V(i) staged; all prev reads done
    if (i + 2 < 16) STAGE_K(kt0 + i + 2, i & 1);
    if (i + 1 < 16) STAGE_V(kt0 + i + 1, (i + 1) & 1);
    const short* Kn = &Kb[(i + 1) & 1][0];
    const short* Vc = &Vb[i & 1][0];
    const bool doqk = (i + 1 < 16);

    // ---- phase 0: exp/pack P rows 0..31 ∥ QK(i+1) rows 0..31, then PV pr=0 ----
    uint2 a0, a1, c0, c1;
    EXPPACK(s[0][0], a0); EXPPACK(s[0][1], a1);
    EXPPACK(s[1][0], c0); EXPPACK(s[1][1], c1);
    if (doqk) {
      __builtin_amdgcn_s_setprio(1);
      QK_N(Kn, 0); QK_N(Kn, 1);
      __builtin_amdgcn_s_setprio(0);
    }
    {
      bf16x8 va[4];
#pragma unroll
      for (int dt = 0; dt < 4; ++dt)
        va[dt] = *(const bf16x8*)&Vc[(dt * 16 + l15) * 64 + co0];
      __builtin_amdgcn_s_setprio(1);
      PV_QG(va, a0, c0, 0);
      PV_QG(va, a1, c1, 1);
      __builtin_amdgcn_s_setprio(0);
    }

    // ---- phase 1: exp/pack P rows 32..63 ∥ QK(i+1) rows 32..63, then PV pr=1 ----
    uint2 a2, a3, c2, c3;
    EXPPACK(s[2][0], a2); EXPPACK(s[2][1], a3);
    EXPPACK(s[3][0], c2); EXPPACK(s[3][1], c3);
    if (doqk) {
      __builtin_amdgcn_s_setprio(1);
      QK_N(Kn, 2); QK_N(Kn, 3);
      __builtin_amdgcn_s_setprio(0);
    }
    {
      bf16x8 va[4];
#pragma unroll
      for (int dt = 0; dt < 4; ++dt)
        va[dt] = *(const bf16x8*)&Vc[(dt * 16 + l15) * 64 + co1];
      __builtin_amdgcn_s_setprio(1);
      PV_QG(va, a2, c2, 0);
      PV_QG(va, a3, c3, 1);
      __builtin_amdgcn_s_setprio(0);
    }
  }

#undef STAGE_K
#undef STAGE_V
#undef QK_N
#undef EXPPACK
#undef PV_QG

#pragma unroll
  for (int qg = 0; qg < 2; ++qg) {
    const float lv = lden[qg][0];           // all rows identical; col l15 = this q
    const float linv = 1.f / lv;
    const int ql = q0 + w * 32 + qg * 16 + l15;
    if (quad == 0)
      lden_g[((size_t)(kz * Bb + b) * Hh + h) * Ll + ql] = lv;
    __hip_bfloat16* dst = o_part + ((size_t)kz * NT + b * Ll + ql) * Dd + h * 64;
#pragma unroll
    for (int dt = 0; dt < 4; ++dt) {
      const uint2 o = make_uint2(
          pack2bf(acc[dt][qg][0] * linv, acc[dt][qg][1] * linv),
          pack2bf(acc[dt][qg][2] * linv, acc[dt][qg][3] * linv));
      *(uint2*)&dst[dt * 16 + quad * 4] = o;
    }
  }
}

// ---------------- combine the two split-K partials -----------------------------------
// aout[n][d] = (l0*O0 + l1*O1) / (l0+l1); one thread per 4 d.
__global__ __launch_bounds__(256) void attn_combine(
    const __hip_bfloat16* __restrict__ o_part, const float* __restrict__ lden_g,
    __hip_bfloat16* __restrict__ aout)
{
  const int i = blockIdx.x * 256 + threadIdx.x;   // NT*Dd/4 = 1,048,576
  const int n = i >> 8, d4 = i & 255;
  const int b = n >> 11, l = n & 2047;
  const int h = d4 >> 4;
  const float l0 = lden_g[((size_t)b * Hh + h) * Ll + l];
  const float l1 = lden_g[((size_t)(Bb + b) * Hh + h) * Ll + l];
  const float inv = 1.f / (l0 + l1);
  const float w0 = l0 * inv, w1 = l1 * inv;
  const uint2 a0 = ((const uint2*)o_part)[i];
  const uint2 a1 = ((const uint2*)o_part)[(NT * (size_t)Dd / 4) + i];
  const float r0 = w0 * bfhalf(a0.x, 0) + w1 * bfhalf(a1.x, 0);
  const float r1 = w0 * bfhalf(a0.x, 1) + w1 * bfhalf(a1.x, 1);
  const float r2 = w0 * bfhalf(a0.y, 0) + w1 * bfhalf(a1.y, 0);
  const float r3 = w0 * bfhalf(a0.y, 1) + w1 * bfhalf(a1.y, 1);
  ((uint2*)aout)[i] = make_uint2(pack2bf(r0, r1), pack2bf(r2, r3));
}

extern "C" void kernel_launch(void* const* d_in, const int* in_sizes, int n_in,
                              void* d_out, int out_size, void* d_ws, size_t ws_size,
                              hipStream_t stream) {
  const float* x     = (const float*)d_in[0];
  const float* p     = (const float*)d_in[1];
  const float* W_qkv = (const float*)d_in[2];
  const float* b_qkv = (const float*)d_in[3];
  const float* W_out = (const float*)d_in[4];
  const float* b_out = (const float*)d_in[5];
  const float* proj  = (const float*)d_in[6];
  float* out = (float*)d_out;

  // workspace overlay (~61 MiB):
  //  [0,8Mi):   phases fp32
  //  [8,16Mi):  p_hi  -> (dead after phases gemm) aout_bf
  //  [16,24Mi): p_lo  -> (dead after phases gemm) vt_g
  //  [24,25Mi): projt_hi   [25,26Mi): projt_lo
  //  [26,34Mi): q_bf   [34,42Mi): k_bf
  //  [42,50Mi): x_bf     -> (dead after qkv gemm) o_part z0
  //  [50,56Mi): wqkv_bf  -> (dead after qkv gemm) o_part z1 [50,58Mi)
  //  [58,60Mi): wout_bf
  //  [60,60.5Mi): lden_g
  char* wsb = (char*)d_ws;
  float*          phases   = (float*)(wsb);
  short*          p_hi     = (short*)(wsb + (8u << 20));
  __hip_bfloat16* aout_bf  = (__hip_bfloat16*)(wsb + (8u << 20));
  short*          p_lo     = (short*)(wsb + (16u << 20));
  __hip_bfloat16* vt_g     = (__hip_bfloat16*)(wsb + (16u << 20));
  short*          projt_hi = (short*)(wsb + (24u << 20));
  short*          projt_lo = (short*)(wsb + (25u << 20));
  __hip_bfloat16* q_bf     = (__hip_bfloat16*)(wsb + (26u << 20));
  __hip_bfloat16* k_bf     = (__hip_bfloat16*)(wsb + (34u << 20));
  __hip_bfloat16* x_bf     = (__hip_bfloat16*)(wsb + (42u << 20));
  __hip_bfloat16* o_part   = (__hip_bfloat16*)(wsb + (42u << 20));
  __hip_bfloat16* wqkv_bf  = (__hip_bfloat16*)(wsb + (50u << 20));
  __hip_bfloat16* wout_bf  = (__hip_bfloat16*)(wsb + (58u << 20));
  float*          lden_g   = (float*)(wsb + (60u << 20));

  // merged input prep
  prep_kernel<<<12416, 256, 0, stream>>>(
      (const float4*)p, (uint2*)p_hi, (uint2*)p_lo,
      proj, projt_hi, projt_lo,
      (const float4*)x, (const float4*)W_qkv, (const float4*)W_out,
      (uint2*)x_bf, (uint2*)wqkv_bf, (uint2*)wout_bf);
  // phases = p @ proj (split-bf16), 64x64 tiles -> 512 blocks (2/CU)
  gemm_nn_split<<<dim3(PH / 64, NT / 64), 256, 0, stream>>>(p_hi, p_lo, projt_hi, projt_lo, phases);
  // qkv GEMM + fused rotary/cast/swizzled V/K epilogue (128n x 64m, 1536 blocks)
  gemm_qkv_fused<<<dim3(D3 / 64, NT / 128), 256, 0, stream>>>(x_bf, wqkv_bf, b_qkv, phases,
                                                              q_bf, k_bf, vt_g);
  // flash attention (split-K halves, pipelined) -> partials
  attn_mfma<<<dim3(Ll / 128, Bb * Hh, 2), 256, 0, stream>>>(q_bf, k_bf, vt_g, o_part, lden_g);
  // combine partials -> aout bf16
  attn_combine<<<4096, 256, 0, stream>>>(o_part, lden_g, aout_bf);
  // out = aout @ W_out^T + b_out (128n x 64m tiles, 512 blocks)
  gemm_bt_64<<<dim3(Dd / 64, NT / 128), 256, 0, stream>>>(aout_bf, wout_bf, b_out, out, Dd, Dd);
}

// Round 14
// 249.308 us; speedup vs baseline: 1.0544x; 1.0047x over previous
//
#include <hip/hip_runtime.h>
#include <hip/hip_bf16.h>
#include <math.h>

namespace {
constexpr int Bb = 2;
constexpr int Ll = 2048;
constexpr int Dd = 1024;
constexpr int Hh = 16;
constexpr int NT = Bb * Ll;   // 4096 tokens
constexpr int D3 = 3 * Dd;    // 3072
constexpr int PH = Dd / 2;    // 512 phases per token
}

typedef __attribute__((ext_vector_type(8))) short bf16x8;
typedef __attribute__((ext_vector_type(4))) float f32x4;

__device__ inline unsigned pack2bf(float a, float b) {
  __hip_bfloat162 t = __float22bfloat162_rn(float2{a, b});
  union { __hip_bfloat162 h; unsigned u; } cv; cv.h = t;
  return cv.u;
}

__device__ inline float bfhalf(unsigned u, int hi) {
  union { unsigned u; float f; } c;
  c.u = hi ? (u & 0xffff0000u) : (u << 16);
  return c.f;
}

__device__ inline void async_cp16(const void* gsrc, void* ldst) {
  __builtin_amdgcn_global_load_lds(
      (const __attribute__((address_space(1))) unsigned int*)gsrc,
      (__attribute__((address_space(3))) unsigned int*)ldst, 16, 0, 0);
}

// ---------------- merged input prep: split_cast(p) + trans_split(proj) + cast3 ------
__global__ __launch_bounds__(256) void prep_kernel(
    const float4* __restrict__ p, uint2* __restrict__ p_hi4, uint2* __restrict__ p_lo4,
    const float* __restrict__ proj, short* __restrict__ th, short* __restrict__ tl,
    const float4* __restrict__ x, const float4* __restrict__ wq, const float4* __restrict__ wo,
    uint2* __restrict__ xd, uint2* __restrict__ wqd, uint2* __restrict__ wod)
{
  __shared__ float Ls[64][65];
  const int bid = blockIdx.x;
  const int tid = threadIdx.x;

  if (bid < 4096) {
    const int i = bid * 256 + tid;
    const float4 f = p[i];
    float hf[4], lf[4];
    const float ff[4] = {f.x, f.y, f.z, f.w};
#pragma unroll
    for (int j = 0; j < 4; ++j) {
      const __hip_bfloat16 h = __float2bfloat16(ff[j]);
      hf[j] = __bfloat162float(h);
      lf[j] = ff[j] - hf[j];
    }
    p_hi4[i] = make_uint2(pack2bf(hf[0], hf[1]), pack2bf(hf[2], hf[3]));
    p_lo4[i] = make_uint2(pack2bf(lf[0], lf[1]), pack2bf(lf[2], lf[3]));
  } else if (bid < 4224) {
    const int bx = bid - 4096;
    const int d0 = (bx & 15) * 64, m0 = (bx >> 4) * 64;
    const int r = tid >> 4, c4 = (tid & 15) * 4;
#pragma unroll
    for (int it = 0; it < 4; ++it) {
      const int row = it * 16 + r;
      const float4 v = *(const float4*)&proj[(size_t)(d0 + row) * PH + m0 + c4];
      Ls[row][c4] = v.x; Ls[row][c4+1] = v.y; Ls[row][c4+2] = v.z; Ls[row][c4+3] = v.w;
    }
    __syncthreads();
#pragma unroll
    for (int it = 0; it < 4; ++it) {
      const int row = it * 16 + r;
      float hf[4], lf[4];
#pragma unroll
      for (int j = 0; j < 4; ++j) {
        const float v = Ls[c4 + j][row];
        const __hip_bfloat16 h = __float2bfloat16(v);
        hf[j] = __bfloat162float(h);
        lf[j] = v - hf[j];
      }
      *(uint2*)&th[(size_t)(m0 + row) * Dd + d0 + c4] = make_uint2(pack2bf(hf[0], hf[1]), pack2bf(hf[2], hf[3]));
      *(uint2*)&tl[(size_t)(m0 + row) * Dd + d0 + c4] = make_uint2(pack2bf(lf[0], lf[1]), pack2bf(lf[2], lf[3]));
    }
  } else {
    int i = (bid - 4224) * 256 + tid;   // covers 2,097,152
    const float4* s; uint2* d;
    if (i < 1048576) { s = x; d = xd; }
    else if (i < 1048576 + 786432) { i -= 1048576; s = wq; d = wqd; }
    else { i -= 1048576 + 786432; s = wo; d = wod; }
    const float4 f = s[i];
    d[i] = make_uint2(pack2bf(f.x, f.y), pack2bf(f.z, f.w));
  }
}

// ---------------- split-bf16 MFMA GEMM for phases: 64n x 64m tile ------------------
// 3-buffer LDS pipeline, lookahead-2, counted vmcnt (4 loads/stage). The
// sched_barrier(0) after the barrier is REQUIRED: without it the compiler
// re-interleaves stage-issues/ds_reads around the hand-counted vmcnt (R7: -10us).
__global__ __launch_bounds__(256) void gemm_nn_split(
    const short* __restrict__ Ah_g, const short* __restrict__ Al_g,
    const short* __restrict__ Wh_g, const short* __restrict__ Wl_g,
    float* __restrict__ C)
{
  __shared__ __align__(16) short Ah[3][64 * 32], Al[3][64 * 32];
  __shared__ __align__(16) short Wh[3][64 * 32], Wl[3][64 * 32];
  const int tid = threadIdx.x;
  const int w = tid >> 6, lane = tid & 63;
  const int l15 = lane & 15, quad = lane >> 4;
  const int n0 = blockIdx.y * 64, m0 = blockIdx.x * 64;

  const int row = tid >> 2, cc = tid & 3;
  const int ksw = (cc ^ (row & 3)) * 8;
  const short* gAh = Ah_g + (size_t)(n0 + row) * Dd + ksw;
  const short* gAl = Al_g + (size_t)(n0 + row) * Dd + ksw;
  const short* gWh = Wh_g + (size_t)(m0 + row) * Dd + ksw;
  const short* gWl = Wl_g + (size_t)(m0 + row) * Dd + ksw;

  f32x4 acc[4];
#pragma unroll
  for (int j = 0; j < 4; ++j) acc[j] = f32x4{0.f, 0.f, 0.f, 0.f};

  const int swq = (quad ^ (l15 & 3)) * 8;

#define STAGE_NN(kv, bf) { \
  async_cp16(gAh + (kv), &Ah[bf][tid * 8]); \
  async_cp16(gAl + (kv), &Al[bf][tid * 8]); \
  async_cp16(gWh + (kv), &Wh[bf][tid * 8]); \
  async_cp16(gWl + (kv), &Wl[bf][tid * 8]); }

  STAGE_NN(0, 0);
  STAGE_NN(32, 1);
  int bi = 0;
  for (int k0 = 0; k0 < Dd; k0 += 32) {
    if (k0 + 32 < Dd) { asm volatile("s_waitcnt vmcnt(4)" ::: "memory"); }
    else              { asm volatile("s_waitcnt vmcnt(0)" ::: "memory"); }
    __builtin_amdgcn_s_barrier();
    __builtin_amdgcn_sched_barrier(0);
    if (k0 + 64 < Dd) { const int bn = (bi + 2 >= 3) ? bi - 1 : bi + 2; STAGE_NN(k0 + 64, bn); }

    bf16x8 ah, al, wh[4], wl[4];
    ah = *(const bf16x8*)&Ah[bi][(w * 16 + l15) * 32 + swq];
    al = *(const bf16x8*)&Al[bi][(w * 16 + l15) * 32 + swq];
#pragma unroll
    for (int j = 0; j < 4; ++j) {
      wh[j] = *(const bf16x8*)&Wh[bi][(j * 16 + l15) * 32 + swq];
      wl[j] = *(const bf16x8*)&Wl[bi][(j * 16 + l15) * 32 + swq];
    }
#pragma unroll
    for (int j = 0; j < 4; ++j) {
      acc[j] = __builtin_amdgcn_mfma_f32_16x16x32_bf16(ah, wh[j], acc[j], 0, 0, 0);
      acc[j] = __builtin_amdgcn_mfma_f32_16x16x32_bf16(ah, wl[j], acc[j], 0, 0, 0);
      acc[j] = __builtin_amdgcn_mfma_f32_16x16x32_bf16(al, wh[j], acc[j], 0, 0, 0);
    }
    bi = (bi == 2) ? 0 : bi + 1;
  }
#undef STAGE_NN

#pragma unroll
  for (int r = 0; r < 4; ++r) {
    float* crow = C + (size_t)(n0 + w * 16 + quad * 4 + r) * PH + m0 + l15;
#pragma unroll
    for (int j = 0; j < 4; ++j) crow[j * 16] = acc[j][r];
  }
}

// ---------------- qkv GEMM: 128n x 64m tile, XCD-swizzled (1536 blocks) -------------
// R14: flat 1D grid with XCD-aware remap swz=(bid&7)*192+(bid>>3) (bijective,
// 1536%8==0). Consecutive HW-dispatched bids round-robin XCDs; after the remap
// each XCD owns a contiguous 192-block chunk = 4 complete n-panels, so every
// 256KB A-panel is fetched from L3 once per XCD that needs it (was 8x) -> cuts
// the ~10 TB/s LDS-fill stream that R13 showed is the shared-resource limiter.
// 3-buffer pipeline, counted vmcnt(3); sched_barrier(0) REQUIRED (R7).
// K and V written in the XOR-swizzled layout the attention kernel expects:
//   K: element (token n, within-head d) stored at d ^ ((n&7)<<3)
//   V^T: element (d-row, token t) stored at (t within 64-group) ^ ((d&7)<<3)
__global__ __launch_bounds__(256) void gemm_qkv_fused(
    const __hip_bfloat16* __restrict__ A, const __hip_bfloat16* __restrict__ W,
    const float* __restrict__ bias, const float* __restrict__ phases,
    __hip_bfloat16* __restrict__ q_bf, __hip_bfloat16* __restrict__ k_bf,
    __hip_bfloat16* __restrict__ vt_g)
{
  __shared__ __align__(16) short As[3][128 * 32];
  __shared__ __align__(16) short Ws[3][64 * 32];
  const int tid = threadIdx.x;
  const int w = tid >> 6, lane = tid & 63;
  const int l15 = lane & 15, quad = lane >> 4;

  const int bid = blockIdx.x;                      // 0..1535
  const int swz = (bid & 7) * 192 + (bid >> 3);    // XCD-contiguous work chunks
  const int m0 = (swz % 48) * 64;
  const int n0 = (swz / 48) * 128;

  const int row = tid >> 2, cc = tid & 3;
  const int ksw = (cc ^ (row & 3)) * 8;
  const short* gA = (const short*)A + (size_t)(n0 + row) * Dd + ksw;
  const short* gW = (const short*)W + (size_t)(m0 + row) * Dd + ksw;

  f32x4 acc[2][4];
#pragma unroll
  for (int i = 0; i < 2; ++i)
#pragma unroll
    for (int j = 0; j < 4; ++j) acc[i][j] = f32x4{0.f, 0.f, 0.f, 0.f};

  const int swq = (quad ^ (l15 & 3)) * 8;

#define STAGE_QKV(kv, bf) { \
  async_cp16(gA + (kv),            &As[bf][tid * 8]); \
  async_cp16(gA + 64 * Dd + (kv),  &As[bf][2048 + tid * 8]); \
  async_cp16(gW + (kv),            &Ws[bf][tid * 8]); }

  STAGE_QKV(0, 0);
  STAGE_QKV(32, 1);
  int bi = 0;
  for (int k0 = 0; k0 < Dd; k0 += 32) {
    if (k0 + 32 < Dd) { asm volatile("s_waitcnt vmcnt(3)" ::: "memory"); }
    else              { asm volatile("s_waitcnt vmcnt(0)" ::: "memory"); }
    __builtin_amdgcn_s_barrier();
    __builtin_amdgcn_sched_barrier(0);
    if (k0 + 64 < Dd) { const int bn = (bi + 2 >= 3) ? bi - 1 : bi + 2; STAGE_QKV(k0 + 64, bn); }

    bf16x8 af[2], bf[4];
#pragma unroll
    for (int i = 0; i < 2; ++i)
      af[i] = *(const bf16x8*)&As[bi][(w * 32 + i * 16 + l15) * 32 + swq];
#pragma unroll
    for (int j = 0; j < 4; ++j)
      bf[j] = *(const bf16x8*)&Ws[bi][(j * 16 + l15) * 32 + swq];
#pragma unroll
    for (int i = 0; i < 2; ++i)
#pragma unroll
      for (int j = 0; j < 4; ++j)
        acc[i][j] = __builtin_amdgcn_mfma_f32_16x16x32_bf16(af[i], bf[j], acc[i][j], 0, 0, 0);
    bi = (bi == 2) ? 0 : bi + 1;
  }
#undef STAGE_QKV

  float bv[4];
#pragma unroll
  for (int j = 0; j < 4; ++j) bv[j] = bias[m0 + j * 16 + l15];

  const int region = m0 >> 10;                 // 0=q, 1=k, 2=v (block-uniform)
  const int h = (m0 & 1023) >> 6;              // m-tile is exactly one head

  if (region < 2) {
    __hip_bfloat16* dst = region == 0 ? q_bf : k_bf;
    const float SC = region == 0 ? 0.18033688011112042f : 1.0f;  // (1/8)*log2(e) on q
    const int dosw = (region == 1);
#pragma unroll
    for (int i = 0; i < 2; ++i)
#pragma unroll
      for (int r = 0; r < 4; ++r) {
        const int n = n0 + w * 32 + i * 16 + quad * 4 + r;
        const int swzk = dosw ? (((quad * 4 + r) & 7) << 3) : 0;   // == (n&7)<<3
        const float* phrow = phases + (size_t)n * PH + h * 32;
        __hip_bfloat16* drow = dst + (size_t)n * Dd + h * 64;
#pragma unroll
        for (int pz = 0; pz < 2; ++pz) {
          const float ph = phrow[pz * 16 + l15];
          float sn, cs;
          __sincosf(ph, &sn, &cs);
          const float a1 = acc[i][pz][r] + bv[pz];
          const float a2 = acc[i][pz + 2][r] + bv[pz + 2];
          drow[(pz * 16 + l15) ^ swzk]      = __float2bfloat16((a1 * cs - a2 * sn) * SC);
          drow[(pz * 16 + 32 + l15) ^ swzk] = __float2bfloat16((a1 * sn + a2 * cs) * SC);
        }
      }
  } else {
    const int bh = (n0 >> 11) * 16 + h;
    const int tokb = (n0 & 2047) + (w >> 1) * 64;     // 64-token group base
    const int loc0 = (w & 1) * 32;                    // token-local base within group
    const int vsw = (l15 & 7) << 3;                   // (d&7)<<3, d = j*16+l15
#pragma unroll
    for (int i = 0; i < 2; ++i)
#pragma unroll
      for (int j = 0; j < 4; ++j) {
        const uint2 o = make_uint2(
            pack2bf(acc[i][j][0] + bv[j], acc[i][j][1] + bv[j]),
            pack2bf(acc[i][j][2] + bv[j], acc[i][j][3] + bv[j]));
        const int d = j * 16 + l15;
        *(uint2*)&vt_g[(size_t)(bh * 64 + d) * Ll + tokb + ((loc0 + i * 16 + quad * 4) ^ vsw)] = o;
      }
  }
}

// ---------------- out-proj GEMM: 128n x 64m tile, 3-buf counted-vmcnt pipeline ------
// 3 loads/stage -> vmcnt(3) steady-state, vmcnt(0) on the last iteration.
__global__ __launch_bounds__(256) void gemm_bt_64(
    const __hip_bfloat16* __restrict__ A, const __hip_bfloat16* __restrict__ W,
    const float* __restrict__ bias, float* __restrict__ C, int K, int M)
{
  __shared__ __align__(16) short As[3][128 * 32];
  __shared__ __align__(16) short Ws[3][64 * 32];
  const int tid = threadIdx.x;
  const int w = tid >> 6, lane = tid & 63;
  const int l15 = lane & 15, quad = lane >> 4;
  const int n0 = blockIdx.y * 128, m0 = blockIdx.x * 64;

  const int row = tid >> 2, cc = tid & 3;
  const int ksw = (cc ^ (row & 3)) * 8;
  const short* gA = (const short*)A + (size_t)(n0 + row) * K + ksw;
  const short* gW = (const short*)W + (size_t)(m0 + row) * K + ksw;

  f32x4 acc[2][4];
#pragma unroll
  for (int i = 0; i < 2; ++i)
#pragma unroll
    for (int j = 0; j < 4; ++j) acc[i][j] = f32x4{0.f, 0.f, 0.f, 0.f};

  const int swq = (quad ^ (l15 & 3)) * 8;

#define STAGE_BT(kv, bf) { \
  async_cp16(gA + (kv),           &As[bf][tid * 8]); \
  async_cp16(gA + 64 * K + (kv),  &As[bf][2048 + tid * 8]); \
  async_cp16(gW + (kv),           &Ws[bf][tid * 8]); }

  STAGE_BT(0, 0);
  STAGE_BT(32, 1);
  int bi = 0;
  for (int k0 = 0; k0 < K; k0 += 32) {
    if (k0 + 32 < K) { asm volatile("s_waitcnt vmcnt(3)" ::: "memory"); }
    else             { asm volatile("s_waitcnt vmcnt(0)" ::: "memory"); }
    __builtin_amdgcn_s_barrier();
    __builtin_amdgcn_sched_barrier(0);
    if (k0 + 64 < K) { const int bn = (bi + 2 >= 3) ? bi - 1 : bi + 2; STAGE_BT(k0 + 64, bn); }

    bf16x8 af[2], bf[4];
#pragma unroll
    for (int i = 0; i < 2; ++i)
      af[i] = *(const bf16x8*)&As[bi][(w * 32 + i * 16 + l15) * 32 + swq];
#pragma unroll
    for (int j = 0; j < 4; ++j)
      bf[j] = *(const bf16x8*)&Ws[bi][(j * 16 + l15) * 32 + swq];
#pragma unroll
    for (int i = 0; i < 2; ++i)
#pragma unroll
      for (int j = 0; j < 4; ++j)
        acc[i][j] = __builtin_amdgcn_mfma_f32_16x16x32_bf16(af[i], bf[j], acc[i][j], 0, 0, 0);
    bi = (bi == 2) ? 0 : bi + 1;
  }
#undef STAGE_BT

  float bv[4];
#pragma unroll
  for (int j = 0; j < 4; ++j) bv[j] = bias[m0 + j * 16 + l15];
#pragma unroll
  for (int i = 0; i < 2; ++i)
#pragma unroll
    for (int r = 0; r < 4; ++r) {
      float* crow = C + (size_t)(n0 + w * 32 + i * 16 + quad * 4 + r) * M + m0 + l15;
#pragma unroll
      for (int j = 0; j < 4; ++j) crow[j * 16] = acc[i][j][r] + bv[j];
    }
}

// ---------------- bf16 MFMA flash attention (split-K, pipelined QK(kt+1) ∥ exp(kt)) -
// Q-tile 128, K-tile 64, blockIdx.z selects kt half [z*16, z*16+16). Grid 1024.
// Software pipeline (T15-style): QK^T of tile kt+1 (MFMA pipe) is issued alongside
// exp2/pack of tile kt (VALU/trans pipe); PV(kt) closes each phase. K is staged
// with lookahead 2 into Kb[2], V with lookahead 1 into Vb[2]; one barrier per kt.
__global__ __launch_bounds__(256) void attn_mfma(
    const __hip_bfloat16* __restrict__ q_bf,
    const __hip_bfloat16* __restrict__ k_bf,
    const __hip_bfloat16* __restrict__ vt_g,
    __hip_bfloat16* __restrict__ o_part,   // [2][NT][Dd] bf16
    float* __restrict__ lden_g)            // [2][Bb][Hh][Ll] fp32
{
  __shared__ __align__(16) short Kb[2][4096];
  __shared__ __align__(16) short Vb[2][4096];

  const int tid = threadIdx.x;
  const int w = tid >> 6;
  const int lane = tid & 63;
  const int l15 = lane & 15;
  const int quad = lane >> 4;

  const int q0 = blockIdx.x * 128;
  const int bh = blockIdx.y;
  const int kz = blockIdx.z;
  const int b = bh >> 4, h = bh & 15;
  const int kt0 = kz * 16;

  bf16x8 qfrag[2][2];
#pragma unroll
  for (int qg = 0; qg < 2; ++qg)
#pragma unroll
    for (int kh = 0; kh < 2; ++kh) {
      const size_t qrow = (size_t)(b * Ll + q0 + w * 32 + qg * 16 + l15);
      qfrag[qg][kh] = *(const bf16x8*)(q_bf + qrow * Dd + h * 64 + kh * 32 + quad * 8);
    }

  f32x4 acc[4][2];
#pragma unroll
  for (int dt = 0; dt < 4; ++dt)
#pragma unroll
    for (int qg = 0; qg < 2; ++qg) acc[dt][qg] = f32x4{0.f, 0.f, 0.f, 0.f};
  f32x4 lden[2] = {f32x4{0.f,0.f,0.f,0.f}, f32x4{0.f,0.f,0.f,0.f}};
  const f32x4 zro = {0.f, 0.f, 0.f, 0.f};
  const short one_bf = (short)0x3F80;           // bf16 1.0
  const bf16x8 ones8 = {one_bf, one_bf, one_bf, one_bf, one_bf, one_bf, one_bf, one_bf};

  // staging: thread tid copies 16B of row (tid>>3) (+32 rows) at byte col (tid&7)*16
  const __hip_bfloat16* ksrc = k_bf + ((size_t)(b * Ll) + (tid >> 3)) * Dd + h * 64 + (tid & 7) * 8;
  const __hip_bfloat16* vsrc = vt_g + ((size_t)(bh * 64) + (tid >> 3)) * Ll + (tid & 7) * 8;
  const int ldst = tid * 8;   // shorts offset within a 4096-short plane

  // swizzled column offsets (shorts): logical col ^ ((row&7)<<3)
  const int sw = (l15 & 7) << 3;
  const int co0 = (quad * 8) ^ sw;
  const int co1 = (32 + quad * 8) ^ sw;

#define STAGE_K(t, bf) { const __hip_bfloat16* kp_ = ksrc + (size_t)(t) * 64 * Dd; \
  async_cp16(kp_, &Kb[bf][ldst]); async_cp16(kp_ + (size_t)32 * Dd, &Kb[bf][2048 + ldst]); }
#define STAGE_V(t, bf) { const __hip_bfloat16* vp_ = vsrc + (size_t)(t) * 64; \
  async_cp16(vp_, &Vb[bf][ldst]); async_cp16(vp_ + (size_t)32 * Ll, &Vb[bf][2048 + ldst]); }

  f32x4 s[4][2];

#define QK_N(Ks, n) { \
  const bf16x8 af0_ = *(const bf16x8*)&(Ks)[((n) * 16 + l15) * 64 + co0]; \
  const bf16x8 af1_ = *(const bf16x8*)&(Ks)[((n) * 16 + l15) * 64 + co1]; \
  s[n][0] = __builtin_amdgcn_mfma_f32_16x16x32_bf16(af0_, qfrag[0][0], zro, 0, 0, 0); \
  s[n][1] = __builtin_amdgcn_mfma_f32_16x16x32_bf16(af0_, qfrag[1][0], zro, 0, 0, 0); \
  s[n][0] = __builtin_amdgcn_mfma_f32_16x16x32_bf16(af1_, qfrag[0][1], s[n][0], 0, 0, 0); \
  s[n][1] = __builtin_amdgcn_mfma_f32_16x16x32_bf16(af1_, qfrag[1][1], s[n][1], 0, 0, 0); }

#define EXPPACK(v, dst) { union { float f; unsigned u; } p0_, p1_, p2_, p3_; \
  p0_.f = __builtin_amdgcn_exp2f((v)[0]); p1_.f = __builtin_amdgcn_exp2f((v)[1]); \
  p2_.f = __builtin_amdgcn_exp2f((v)[2]); p3_.f = __builtin_amdgcn_exp2f((v)[3]); \
  dst = make_uint2(__builtin_amdgcn_perm(p1_.u, p0_.u, 0x07060302u), \
                   __builtin_amdgcn_perm(p3_.u, p2_.u, 0x07060302u)); }

#define PV_QG(va, aU, cU, qg) { \
  auto rx32_ = __builtin_amdgcn_permlane32_swap((aU).x, (cU).x, false, false); \
  auto rx16_ = __builtin_amdgcn_permlane16_swap(rx32_[0], rx32_[1], false, false); \
  auto ry32_ = __builtin_amdgcn_permlane32_swap((aU).y, (cU).y, false, false); \
  auto ry16_ = __builtin_amdgcn_permlane16_swap(ry32_[0], ry32_[1], false, false); \
  union { unsigned u[4]; bf16x8 v; } pb_; \
  pb_.u[0] = rx16_[0]; pb_.u[1] = ry16_[0]; pb_.u[2] = rx16_[1]; pb_.u[3] = ry16_[1]; \
  lden[qg] = __builtin_amdgcn_mfma_f32_16x16x32_bf16(ones8, pb_.v, lden[qg], 0, 0, 0); \
  acc[0][qg] = __builtin_amdgcn_mfma_f32_16x16x32_bf16(va[0], pb_.v, acc[0][qg], 0, 0, 0); \
  acc[1][qg] = __builtin_amdgcn_mfma_f32_16x16x32_bf16(va[1], pb_.v, acc[1][qg], 0, 0, 0); \
  acc[2][qg] = __builtin_amdgcn_mfma_f32_16x16x32_bf16(va[2], pb_.v, acc[2][qg], 0, 0, 0); \
  acc[3][qg] = __builtin_amdgcn_mfma_f32_16x16x32_bf16(va[3], pb_.v, acc[3][qg], 0, 0, 0); }

  // prologue: K(0) -> Kb[0]; after barrier, start K(1),V(0) and compute QK(0)
  STAGE_K(kt0, 0);
  __syncthreads();
  STAGE_K(kt0 + 1, 1);
  STAGE_V(kt0, 0);
  __builtin_amdgcn_s_setprio(1);
  QK_N(Kb[0], 0); QK_N(Kb[0], 1); QK_N(Kb[0], 2); QK_N(Kb[0], 3);
  __builtin_amdgcn_s_setprio(0);

  for (int i = 0; i < 16; ++i) {
    __syncthreads();   // implicit vmcnt(0): K(i+1),V(i) staged; all prev reads done
    if (i + 2 < 16) STAGE_K(kt0 + i + 2, i & 1);
    if (i + 1 < 16) STAGE_V(kt0 + i + 1, (i + 1) & 1);
    const short* Kn = &Kb[(i + 1) & 1][0];
    const short* Vc = &Vb[i & 1][0];
    const bool doqk = (i + 1 < 16);

    // ---- phase 0: exp/pack P rows 0..31 ∥ QK(i+1) rows 0..31, then PV pr=0 ----
    uint2 a0, a1, c0, c1;
    EXPPACK(s[0][0], a0); EXPPACK(s[0][1], a1);
    EXPPACK(s[1][0], c0); EXPPACK(s[1][1], c1);
    if (doqk) {
      __builtin_amdgcn_s_setprio(1);
      QK_N(Kn, 0); QK_N(Kn, 1);
      __builtin_amdgcn_s_setprio(0);
    }
    {
      bf16x8 va[4];
#pragma unroll
      for (int dt = 0; dt < 4; ++dt)
        va[dt] = *(const bf16x8*)&Vc[(dt * 16 + l15) * 64 + co0];
      __builtin_amdgcn_s_setprio(1);
      PV_QG(va, a0, c0, 0);
      PV_QG(va, a1, c1, 1);
      __builtin_amdgcn_s_setprio(0);
    }

    // ---- phase 1: exp/pack P rows 32..63 ∥ QK(i+1) rows 32..63, then PV pr=1 ----
    uint2 a2, a3, c2, c3;
    EXPPACK(s[2][0], a2); EXPPACK(s[2][1], a3);
    EXPPACK(s[3][0], c2); EXPPACK(s[3][1], c3);
    if (doqk) {
      __builtin_amdgcn_s_setprio(1);
      QK_N(Kn, 2); QK_N(Kn, 3);
      __builtin_amdgcn_s_setprio(0);
    }
    {
      bf16x8 va[4];
#pragma unroll
      for (int dt = 0; dt < 4; ++dt)
        va[dt] = *(const bf16x8*)&Vc[(dt * 16 + l15) * 64 + co1];
      __builtin_amdgcn_s_setprio(1);
      PV_QG(va, a2, c2, 0);
      PV_QG(va, a3, c3, 1);
      __builtin_amdgcn_s_setprio(0);
    }
  }

#undef STAGE_K
#undef STAGE_V
#undef QK_N
#undef EXPPACK
#undef PV_QG

#pragma unroll
  for (int qg = 0; qg < 2; ++qg) {
    const float lv = lden[qg][0];           // all rows identical; col l15 = this q
    const float linv = 1.f / lv;
    const int ql = q0 + w * 32 + qg * 16 + l15;
    if (quad == 0)
      lden_g[((size_t)(kz * Bb + b) * Hh + h) * Ll + ql] = lv;
    __hip_bfloat16* dst = o_part + ((size_t)kz * NT + b * Ll + ql) * Dd + h * 64;
#pragma unroll
    for (int dt = 0; dt < 4; ++dt) {
      const uint2 o = make_uint2(
          pack2bf(acc[dt][qg][0] * linv, acc[dt][qg][1] * linv),
          pack2bf(acc[dt][qg][2] * linv, acc[dt][qg][3] * linv));
      *(uint2*)&dst[dt * 16 + quad * 4] = o;
    }
  }
}

// ---------------- combine the two split-K partials -----------------------------------
// aout[n][d] = (l0*O0 + l1*O1) / (l0+l1); one thread per 4 d.
__global__ __launch_bounds__(256) void attn_combine(
    const __hip_bfloat16* __restrict__ o_part, const float* __restrict__ lden_g,
    __hip_bfloat16* __restrict__ aout)
{
  const int i = blockIdx.x * 256 + threadIdx.x;   // NT*Dd/4 = 1,048,576
  const int n = i >> 8, d4 = i & 255;
  const int b = n >> 11, l = n & 2047;
  const int h = d4 >> 4;
  const float l0 = lden_g[((size_t)b * Hh + h) * Ll + l];
  const float l1 = lden_g[((size_t)(Bb + b) * Hh + h) * Ll + l];
  const float inv = 1.f / (l0 + l1);
  const float w0 = l0 * inv, w1 = l1 * inv;
  const uint2 a0 = ((const uint2*)o_part)[i];
  const uint2 a1 = ((const uint2*)o_part)[(NT * (size_t)Dd / 4) + i];
  const float r0 = w0 * bfhalf(a0.x, 0) + w1 * bfhalf(a1.x, 0);
  const float r1 = w0 * bfhalf(a0.x, 1) + w1 * bfhalf(a1.x, 1);
  const float r2 = w0 * bfhalf(a0.y, 0) + w1 * bfhalf(a1.y, 0);
  const float r3 = w0 * bfhalf(a0.y, 1) + w1 * bfhalf(a1.y, 1);
  ((uint2*)aout)[i] = make_uint2(pack2bf(r0, r1), pack2bf(r2, r3));
}

extern "C" void kernel_launch(void* const* d_in, const int* in_sizes, int n_in,
                              void* d_out, int out_size, void* d_ws, size_t ws_size,
                              hipStream_t stream) {
  const float* x     = (const float*)d_in[0];
  const float* p     = (const float*)d_in[1];
  const float* W_qkv = (const float*)d_in[2];
  const float* b_qkv = (const float*)d_in[3];
  const float* W_out = (const float*)d_in[4];
  const float* b_out = (const float*)d_in[5];
  const float* proj  = (const float*)d_in[6];
  float* out = (float*)d_out;

  // workspace overlay (~61 MiB):
  //  [0,8Mi):   phases fp32
  //  [8,16Mi):  p_hi  -> (dead after phases gemm) aout_bf
  //  [16,24Mi): p_lo  -> (dead after phases gemm) vt_g
  //  [24,25Mi): projt_hi   [25,26Mi): projt_lo
  //  [26,34Mi): q_bf   [34,42Mi): k_bf
  //  [42,50Mi): x_bf     -> (dead after qkv gemm) o_part z0
  //  [50,56Mi): wqkv_bf  -> (dead after qkv gemm) o_part z1 [50,58Mi)
  //  [58,60Mi): wout_bf
  //  [60,60.5Mi): lden_g
  char* wsb = (char*)d_ws;
  float*          phases   = (float*)(wsb);
  short*          p_hi     = (short*)(wsb + (8u << 20));
  __hip_bfloat16* aout_bf  = (__hip_bfloat16*)(wsb + (8u << 20));
  short*          p_lo     = (short*)(wsb + (16u << 20));
  __hip_bfloat16* vt_g     = (__hip_bfloat16*)(wsb + (16u << 20));
  short*          projt_hi = (short*)(wsb + (24u << 20));
  short*          projt_lo = (short*)(wsb + (25u << 20));
  __hip_bfloat16* q_bf     = (__hip_bfloat16*)(wsb + (26u << 20));
  __hip_bfloat16* k_bf     = (__hip_bfloat16*)(wsb + (34u << 20));
  __hip_bfloat16* x_bf     = (__hip_bfloat16*)(wsb + (42u << 20));
  __hip_bfloat16* o_part   = (__hip_bfloat16*)(wsb + (42u << 20));
  __hip_bfloat16* wqkv_bf  = (__hip_bfloat16*)(wsb + (50u << 20));
  __hip_bfloat16* wout_bf  = (__hip_bfloat16*)(wsb + (58u << 20));
  float*          lden_g   = (float*)(wsb + (60u << 20));

  // merged input prep
  prep_kernel<<<12416, 256, 0, stream>>>(
      (const float4*)p, (uint2*)p_hi, (uint2*)p_lo,
      proj, projt_hi, projt_lo,
      (const float4*)x, (const float4*)W_qkv, (const float4*)W_out,
      (uint2*)x_bf, (uint2*)wqkv_bf, (uint2*)wout_bf);
  // phases = p @ proj (split-bf16), 64x64 tiles -> 512 blocks (2/CU)
  gemm_nn_split<<<dim3(PH / 64, NT / 64), 256, 0, stream>>>(p_hi, p_lo, projt_hi, projt_lo, phases);
  // qkv GEMM + fused rotary/cast/swizzled V/K epilogue (XCD-swizzled 1536 blocks)
  gemm_qkv_fused<<<1536, 256, 0, stream>>>(x_bf, wqkv_bf, b_qkv, phases, q_bf, k_bf, vt_g);
  // flash attention (split-K halves, pipelined) -> partials
  attn_mfma<<<dim3(Ll / 128, Bb * Hh, 2), 256, 0, stream>>>(q_bf, k_bf, vt_g, o_part, lden_g);
  // combine partials -> aout bf16
  attn_combine<<<4096, 256, 0, stream>>>(o_part, lden_g, aout_bf);
  // out = aout @ W_out^T + b_out (128n x 64m tiles, 512 blocks)
  gemm_bt_64<<<dim3(Dd / 64, NT / 128), 256, 0, stream>>>(aout_bf, wout_bf, b_out, out, Dd, Dd);
}